// Round 1
// baseline (923.272 us; speedup 1.0000x reference)
//
#include <hip/hip_runtime.h>
#include <hip/hip_bf16.h>
#include <math.h>

// Problem constants (from reference setup_inputs)
#define ND 4      // batch n
#define CL 1024   // sequence length c
#define DD 768    // hidden d
#define HH 12     // heads h
#define EE 32     // entities E
#define MMEN 4    // mentions M
#define PP 256    // pairs P
#define EMBD 768  // EMB
#define KBL 12    // K = EMB/BLOCK
#define OUTD 97   // output classes
#define RTOT (ND*PP)  // 1024 rows

// ---------------------------------------------------------------
// 1. ent_emb[i,e,dd] = logsumexp_m seq[i, mpos[i,e,m], dd]
// ---------------------------------------------------------------
__global__ __launch_bounds__(256) void k_ent_emb(const float* __restrict__ seq,
    const int* __restrict__ mpos, float* __restrict__ ent_emb)
{
  int idx = blockIdx.x*256 + threadIdx.x;
  if (idx >= ND*EE*DD) return;
  int dd = idx % DD;
  int e  = (idx / DD) % EE;
  int i  = idx / (DD*EE);
  const int* mp = mpos + (i*EE + e)*MMEN;
  float v[MMEN];
  float mx = -1e30f;
  #pragma unroll
  for (int m=0;m<MMEN;m++){
    v[m] = seq[(i*CL + mp[m])*DD + dd];
    mx = fmaxf(mx, v[m]);
  }
  float s = 0.f;
  #pragma unroll
  for (int m=0;m<MMEN;m++) s += expf(v[m]-mx);
  ent_emb[idx] = mx + logf(s);
}

// ---------------------------------------------------------------
// 2. ent_att[i,e,head,j] = mean_m attn[i, head, mpos[i,e,m], j]
// ---------------------------------------------------------------
__global__ __launch_bounds__(256) void k_ent_att(const float* __restrict__ attn,
    const int* __restrict__ mpos, float* __restrict__ ent_att)
{
  int idx = blockIdx.x*256 + threadIdx.x;
  if (idx >= ND*EE*HH*CL) return;
  int j    = idx % CL;
  int head = (idx / CL) % HH;
  int e    = (idx / (CL*HH)) % EE;
  int i    = idx / (CL*HH*EE);
  const int* mp = mpos + (i*EE + e)*MMEN;
  float s = 0.f;
  #pragma unroll
  for (int m=0;m<MMEN;m++)
    s += attn[((size_t)(i*HH + head)*CL + mp[m])*CL + j];
  ent_att[idx] = s * (1.f/MMEN);
}

// ---------------------------------------------------------------
// 3. ht_att[i,p,j] = normalize_j( mean_head ent_att[i,he,head,j]*ent_att[i,te,head,j] )
//    one block (256 thr) per (i,p); each thread owns 4 j's
// ---------------------------------------------------------------
__global__ __launch_bounds__(256) void k_ht_att(const float* __restrict__ ent_att,
    const int* __restrict__ hts, float* __restrict__ ht_att)
{
  int bp = blockIdx.x;            // i*PP + p
  int i  = bp / PP;
  int tid = threadIdx.x;
  int he = hts[bp*2+0];
  int te = hts[bp*2+1];
  const float* ha = ent_att + ((size_t)(i*EE + he)*HH)*CL;
  const float* ta = ent_att + ((size_t)(i*EE + te)*HH)*CL;
  float v[4];
  #pragma unroll
  for (int q=0;q<4;q++){
    int j = tid + q*256;
    float s = 0.f;
    #pragma unroll
    for (int head=0; head<HH; head++)
      s += ha[head*CL + j] * ta[head*CL + j];
    v[q] = s * (1.f/HH);
  }
  float part = v[0]+v[1]+v[2]+v[3];
  #pragma unroll
  for (int off=32; off>0; off>>=1) part += __shfl_down(part, off, 64);
  __shared__ float wsum[4];
  __shared__ float tot_s;
  int lane = tid & 63, wv = tid >> 6;
  if (lane==0) wsum[wv] = part;
  __syncthreads();
  if (tid==0) tot_s = wsum[0]+wsum[1]+wsum[2]+wsum[3];
  __syncthreads();
  float inv = 1.f/(tot_s + 1e-30f);
  #pragma unroll
  for (int q=0;q<4;q++){
    int j = tid + q*256;
    ht_att[(size_t)bp*CL + j] = v[q]*inv;
  }
}

// ---------------------------------------------------------------
// 4. rs[i,p,dd] = sum_j ht_att[i,p,j] * seq[i,j,dd]   (per-doc GEMM 256x1024x768)
//    BM=BN=64, BK=16, 16x16 threads, 4x4 microtile
// ---------------------------------------------------------------
__global__ __launch_bounds__(256) void k_gemm_rs(const float* __restrict__ ht_att,
    const float* __restrict__ seq, float* __restrict__ rs)
{
  const int rt = blockIdx.x;      // 0..3 (row tiles of P=256)
  const int ct = blockIdx.y;      // 0..11 (col tiles of 768)
  const int doc = blockIdx.z;     // 0..3
  const float* A = ht_att + (size_t)doc*PP*CL;   // [256,1024]
  const float* B = seq    + (size_t)doc*CL*DD;   // [1024,768]
  float* Cc      = rs     + (size_t)doc*PP*DD;
  const int row0 = rt*64, col0 = ct*64;
  __shared__ float As[16][68];
  __shared__ float Bs[16][64];
  int tx = threadIdx.x, ty = threadIdx.y;
  int tid = ty*16 + tx;
  float acc[4][4] = {};
  for (int k0=0; k0<CL; k0+=16){
    int kk = tid & 15, rbase = tid >> 4;
    #pragma unroll
    for (int q=0;q<4;q++){
      int r = rbase + q*16;
      As[kk][r] = A[(size_t)(row0+r)*CL + k0+kk];
    }
    int colB = tid & 63, kb = tid >> 6;
    #pragma unroll
    for (int q=0;q<4;q++){
      int kkb = kb + q*4;
      Bs[kkb][colB] = B[(size_t)(k0+kkb)*DD + col0+colB];
    }
    __syncthreads();
    #pragma unroll
    for (int kk2=0;kk2<16;kk2++){
      float a[4], b[4];
      #pragma unroll
      for (int m=0;m<4;m++) a[m] = As[kk2][ty*4+m];
      #pragma unroll
      for (int nn=0;nn<4;nn++) b[nn] = Bs[kk2][tx*4+nn];
      #pragma unroll
      for (int m=0;m<4;m++)
        #pragma unroll
        for (int nn=0;nn<4;nn++) acc[m][nn] += a[m]*b[nn];
    }
    __syncthreads();
  }
  #pragma unroll
  for (int m=0;m<4;m++){
    int row = row0 + ty*4+m;
    #pragma unroll
    for (int nn=0;nn<4;nn++){
      int col = col0 + tx*4+nn;
      Cc[(size_t)row*DD + col] = acc[m][nn];
    }
  }
}

// ---------------------------------------------------------------
// 5. A_head[r,kk] = kk<768 ? ent_emb[doc, hts[r,0], kk] : rs[r, kk-768]
//    A_tail analogous with hts[r,1]
// ---------------------------------------------------------------
__global__ __launch_bounds__(256) void k_prepare_ab(const float* __restrict__ ent_emb,
    const float* __restrict__ rs, const int* __restrict__ hts,
    float* __restrict__ A_head, float* __restrict__ A_tail)
{
  int idx = blockIdx.x*256 + threadIdx.x;
  if (idx >= RTOT*1536) return;
  int kk = idx % 1536;
  int r  = idx / 1536;
  int doc = r / PP;
  int he = hts[r*2+0];
  int te = hts[r*2+1];
  float vh, vt;
  if (kk < DD){
    vh = ent_emb[(size_t)(doc*EE + he)*DD + kk];
    vt = ent_emb[(size_t)(doc*EE + te)*DD + kk];
  } else {
    float v = rs[(size_t)r*DD + (kk-DD)];
    vh = v; vt = v;
  }
  A_head[idx] = vh;
  A_tail[idx] = vt;
}

// ---------------------------------------------------------------
// 6. hs2 = tanh(A_head @ W_head + b_head); ts2 analogous (z picks head/tail)
//    M=1024, N=768, K=1536
// ---------------------------------------------------------------
__global__ __launch_bounds__(256) void k_gemm_ht(
    const float* __restrict__ A_head, const float* __restrict__ A_tail,
    const float* __restrict__ W_head, const float* __restrict__ W_tail,
    const float* __restrict__ b_head, const float* __restrict__ b_tail,
    float* __restrict__ hs2, float* __restrict__ ts2)
{
  const int rt = blockIdx.x;      // 0..15
  const int ct = blockIdx.y;      // 0..11
  const int z  = blockIdx.z;      // 0..1
  const float* A    = z ? A_tail : A_head;
  const float* W    = z ? W_tail : W_head;
  const float* bias = z ? b_tail : b_head;
  float* Cc         = z ? ts2    : hs2;
  const int row0 = rt*64, col0 = ct*64;
  __shared__ float As[16][68];
  __shared__ float Bs[16][64];
  int tx = threadIdx.x, ty = threadIdx.y;
  int tid = ty*16 + tx;
  float acc[4][4] = {};
  for (int k0=0; k0<1536; k0+=16){
    int kk = tid & 15, rbase = tid >> 4;
    #pragma unroll
    for (int q=0;q<4;q++){
      int r = rbase + q*16;
      As[kk][r] = A[(size_t)(row0+r)*1536 + k0+kk];
    }
    int colB = tid & 63, kb = tid >> 6;
    #pragma unroll
    for (int q=0;q<4;q++){
      int kkb = kb + q*4;
      Bs[kkb][colB] = W[(size_t)(k0+kkb)*DD + col0+colB];
    }
    __syncthreads();
    #pragma unroll
    for (int kk2=0;kk2<16;kk2++){
      float a[4], b[4];
      #pragma unroll
      for (int m=0;m<4;m++) a[m] = As[kk2][ty*4+m];
      #pragma unroll
      for (int nn=0;nn<4;nn++) b[nn] = Bs[kk2][tx*4+nn];
      #pragma unroll
      for (int m=0;m<4;m++)
        #pragma unroll
        for (int nn=0;nn<4;nn++) acc[m][nn] += a[m]*b[nn];
    }
    __syncthreads();
  }
  #pragma unroll
  for (int m=0;m<4;m++){
    int row = row0 + ty*4+m;
    #pragma unroll
    for (int nn=0;nn<4;nn++){
      int col = col0 + tx*4+nn;
      Cc[(size_t)row*DD + col] = tanhf(acc[m][nn] + bias[col]);
    }
  }
}

// ---------------------------------------------------------------
// 7a. logits init with bias
// ---------------------------------------------------------------
__global__ __launch_bounds__(256) void k_init_logits(const float* __restrict__ b_bil,
    float* __restrict__ out)
{
  int idx = blockIdx.x*256 + threadIdx.x;
  if (idx >= RTOT*OUTD) return;
  out[idx] = b_bil[idx % OUTD];
}

// ---------------------------------------------------------------
// 7b. bilinear: logits[r,o] += sum_{i,j} hs2[r,kb*64+i]*ts2[r,kb*64+j]*W_bil[(kb*4096+i*64+j)*97+o]
//     GEMM over t=(i,j) in [0,4096) with A-tile computed on the fly in LDS.
//     grid (rowtile 16, coltile 2, kb 12); split-K via fp32 atomics.
// ---------------------------------------------------------------
__global__ __launch_bounds__(256) void k_bilinear(
    const float* __restrict__ hs2, const float* __restrict__ ts2,
    const float* __restrict__ W_bil, float* __restrict__ logits)
{
  const int rt = blockIdx.x;   // 0..15
  const int ct = blockIdx.y;   // 0..1
  const int kb = blockIdx.z;   // 0..11
  __shared__ float b1s[64][64];
  __shared__ float b2s[64][64];
  __shared__ float As[16][68];
  __shared__ float Ws[16][64];
  int tx = threadIdx.x, ty = threadIdx.y;
  int tid = ty*16 + tx;
  const int col0 = ct*64;
  // stage the hs2/ts2 64-row, 64-col (this kb) slabs
  #pragma unroll
  for (int q=0;q<16;q++){
    int e = tid + 256*q;       // 0..4095
    int r = e >> 6, i = e & 63;
    b1s[r][i] = hs2[(size_t)(rt*64+r)*EMBD + kb*64 + i];
    b2s[r][i] = ts2[(size_t)(rt*64+r)*EMBD + kb*64 + i];
  }
  __syncthreads();
  float acc[4][4] = {};
  for (int t0=0; t0<4096; t0+=16){
    int i0 = t0 >> 6, j0 = t0 & 63;   // i constant across the 16-chunk
    int kk = tid & 15, rbase = tid >> 4;
    #pragma unroll
    for (int q=0;q<4;q++){
      int r = rbase + 16*q;
      As[kk][r] = b1s[r][i0] * b2s[r][j0+kk];
    }
    int colW = tid & 63, kw = tid >> 6;
    #pragma unroll
    for (int q=0;q<4;q++){
      int kkw = kw + 4*q;
      int t = t0 + kkw;
      int o = col0 + colW;
      Ws[kkw][colW] = (o < OUTD) ? W_bil[(size_t)(kb*4096 + t)*OUTD + o] : 0.f;
    }
    __syncthreads();
    #pragma unroll
    for (int kk2=0;kk2<16;kk2++){
      float a[4], b[4];
      #pragma unroll
      for (int m=0;m<4;m++) a[m] = As[kk2][ty*4+m];
      #pragma unroll
      for (int nn=0;nn<4;nn++) b[nn] = Ws[kk2][tx*4+nn];
      #pragma unroll
      for (int m=0;m<4;m++)
        #pragma unroll
        for (int nn=0;nn<4;nn++) acc[m][nn] += a[m]*b[nn];
    }
    __syncthreads();
  }
  #pragma unroll
  for (int m=0;m<4;m++){
    int row = rt*64 + ty*4+m;
    #pragma unroll
    for (int nn=0;nn<4;nn++){
      int o = col0 + tx*4+nn;
      if (o < OUTD) atomicAdd(&logits[(size_t)row*OUTD + o], acc[m][nn]);
    }
  }
}

// ---------------------------------------------------------------
extern "C" void kernel_launch(void* const* d_in, const int* in_sizes, int n_in,
                              void* d_out, int out_size, void* d_ws, size_t ws_size,
                              hipStream_t stream)
{
  const float* seq    = (const float*)d_in[0];
  const float* attn   = (const float*)d_in[1];
  const int*   mpos   = (const int*)d_in[2];
  const int*   hts    = (const int*)d_in[3];
  const float* W_head = (const float*)d_in[4];
  const float* b_head = (const float*)d_in[5];
  const float* W_tail = (const float*)d_in[6];
  const float* b_tail = (const float*)d_in[7];
  const float* W_bil  = (const float*)d_in[8];
  const float* b_bil  = (const float*)d_in[9];
  float* logits = (float*)d_out;

  float* ws      = (float*)d_ws;
  float* ent_emb = ws;                                   // 4*32*768      = 98304
  float* ent_att = ent_emb + ND*EE*DD;                   // 4*32*12*1024  = 1572864
  float* ht_att  = ent_att + (size_t)ND*EE*HH*CL;        // 4*256*1024    = 1048576
  float* rs      = ht_att  + (size_t)ND*PP*CL;           // 1024*768      = 786432
  float* A_head  = rs      + (size_t)RTOT*DD;            // 1024*1536     = 1572864
  float* A_tail  = A_head  + (size_t)RTOT*1536;          // 1024*1536     = 1572864
  float* hs2     = A_tail  + (size_t)RTOT*1536;          // 1024*768      = 786432
  float* ts2     = hs2     + (size_t)RTOT*EMBD;          // 1024*768      = 786432
  // total: 8,224,768 floats = 31.4 MiB of d_ws

  k_ent_emb<<<(ND*EE*DD+255)/256, 256, 0, stream>>>(seq, mpos, ent_emb);
  k_ent_att<<<(ND*EE*HH*CL+255)/256, 256, 0, stream>>>(attn, mpos, ent_att);
  k_ht_att<<<ND*PP, 256, 0, stream>>>(ent_att, hts, ht_att);
  k_gemm_rs<<<dim3(PP/64, DD/64, ND), dim3(16,16), 0, stream>>>(ht_att, seq, rs);
  k_prepare_ab<<<(RTOT*1536+255)/256, 256, 0, stream>>>(ent_emb, rs, hts, A_head, A_tail);
  k_gemm_ht<<<dim3(RTOT/64, DD/64, 2), dim3(16,16), 0, stream>>>(
      A_head, A_tail, W_head, W_tail, b_head, b_tail, hs2, ts2);
  k_init_logits<<<(RTOT*OUTD+255)/256, 256, 0, stream>>>(b_bil, logits);
  k_bilinear<<<dim3(RTOT/64, 2, KBL), dim3(16,16), 0, stream>>>(hs2, ts2, W_bil, logits);
}

// Round 2
// 539.806 us; speedup vs baseline: 1.7104x; 1.7104x over previous
//
#include <hip/hip_runtime.h>
#include <hip/hip_bf16.h>
#include <math.h>

// Problem constants (from reference setup_inputs)
#define ND 4      // batch n
#define CL 1024   // sequence length c
#define DD 768    // hidden d
#define HH 12     // heads h
#define EE 32     // entities E
#define MMEN 4    // mentions M
#define PP 256    // pairs P
#define EMBD 768  // EMB
#define KBL 12    // K = EMB/BLOCK
#define OUTD 97   // output classes
#define RTOT (ND*PP)  // 1024 rows

typedef __attribute__((ext_vector_type(8))) short short8;
typedef __attribute__((ext_vector_type(4))) float f32x4;

static __device__ inline float bf16u_to_f(unsigned v){
  union { unsigned u; float f; } c; c.u = v << 16; return c.f;
}
static __device__ inline unsigned f_to_bf16u(float f){
  union { float f; unsigned u; } c; c.f = f;
  return (c.u + 0x7fffu + ((c.u >> 16) & 1u)) >> 16;
}

// ---------------------------------------------------------------
// 1. ent_emb[i,e,dd] = logsumexp_m seq[i, mpos[i,e,m], dd]
// ---------------------------------------------------------------
__global__ __launch_bounds__(256) void k_ent_emb(const float* __restrict__ seq,
    const int* __restrict__ mpos, float* __restrict__ ent_emb)
{
  int idx = blockIdx.x*256 + threadIdx.x;
  if (idx >= ND*EE*DD) return;
  int dd = idx % DD;
  int e  = (idx / DD) % EE;
  int i  = idx / (DD*EE);
  const int* mp = mpos + (i*EE + e)*MMEN;
  float v[MMEN];
  float mx = -1e30f;
  #pragma unroll
  for (int m=0;m<MMEN;m++){
    v[m] = seq[(i*CL + mp[m])*DD + dd];
    mx = fmaxf(mx, v[m]);
  }
  float s = 0.f;
  #pragma unroll
  for (int m=0;m<MMEN;m++) s += expf(v[m]-mx);
  ent_emb[idx] = mx + logf(s);
}

// ---------------------------------------------------------------
// 2. ent_att[i,e,head,j] = mean_m attn[i, head, mpos[i,e,m], j]
// ---------------------------------------------------------------
__global__ __launch_bounds__(256) void k_ent_att(const float* __restrict__ attn,
    const int* __restrict__ mpos, float* __restrict__ ent_att)
{
  int idx = blockIdx.x*256 + threadIdx.x;
  if (idx >= ND*EE*HH*CL) return;
  int j    = idx % CL;
  int head = (idx / CL) % HH;
  int e    = (idx / (CL*HH)) % EE;
  int i    = idx / (CL*HH*EE);
  const int* mp = mpos + (i*EE + e)*MMEN;
  float s = 0.f;
  #pragma unroll
  for (int m=0;m<MMEN;m++)
    s += attn[((size_t)(i*HH + head)*CL + mp[m])*CL + j];
  ent_att[idx] = s * (1.f/MMEN);
}

// ---------------------------------------------------------------
// 3. ht_att[i,p,j] = normalize_j( mean_head ent_att[i,he,head,j]*ent_att[i,te,head,j] )
// ---------------------------------------------------------------
__global__ __launch_bounds__(256) void k_ht_att(const float* __restrict__ ent_att,
    const int* __restrict__ hts, float* __restrict__ ht_att)
{
  int bp = blockIdx.x;            // i*PP + p
  int i  = bp / PP;
  int tid = threadIdx.x;
  int he = hts[bp*2+0];
  int te = hts[bp*2+1];
  const float* ha = ent_att + ((size_t)(i*EE + he)*HH)*CL;
  const float* ta = ent_att + ((size_t)(i*EE + te)*HH)*CL;
  float v[4];
  #pragma unroll
  for (int q=0;q<4;q++){
    int j = tid + q*256;
    float s = 0.f;
    #pragma unroll
    for (int head=0; head<HH; head++)
      s += ha[head*CL + j] * ta[head*CL + j];
    v[q] = s * (1.f/HH);
  }
  float part = v[0]+v[1]+v[2]+v[3];
  #pragma unroll
  for (int off=32; off>0; off>>=1) part += __shfl_down(part, off, 64);
  __shared__ float wsum[4];
  __shared__ float tot_s;
  int lane = tid & 63, wv = tid >> 6;
  if (lane==0) wsum[wv] = part;
  __syncthreads();
  if (tid==0) tot_s = wsum[0]+wsum[1]+wsum[2]+wsum[3];
  __syncthreads();
  float inv = 1.f/(tot_s + 1e-30f);
  #pragma unroll
  for (int q=0;q<4;q++){
    int j = tid + q*256;
    ht_att[(size_t)bp*CL + j] = v[q]*inv;
  }
}

// ---------------------------------------------------------------
// 4. rs[i,p,dd] = sum_j ht_att[i,p,j] * seq[i,j,dd]   (per-doc GEMM 256x1024x768)
// ---------------------------------------------------------------
__global__ __launch_bounds__(256) void k_gemm_rs(const float* __restrict__ ht_att,
    const float* __restrict__ seq, float* __restrict__ rs)
{
  const int rt = blockIdx.x;      // 0..3
  const int ct = blockIdx.y;      // 0..11
  const int doc = blockIdx.z;     // 0..3
  const float* A = ht_att + (size_t)doc*PP*CL;
  const float* B = seq    + (size_t)doc*CL*DD;
  float* Cc      = rs     + (size_t)doc*PP*DD;
  const int row0 = rt*64, col0 = ct*64;
  __shared__ float As[16][68];
  __shared__ float Bs[16][64];
  int tx = threadIdx.x, ty = threadIdx.y;
  int tid = ty*16 + tx;
  float acc[4][4] = {};
  for (int k0=0; k0<CL; k0+=16){
    int kk = tid & 15, rbase = tid >> 4;
    #pragma unroll
    for (int q=0;q<4;q++){
      int r = rbase + q*16;
      As[kk][r] = A[(size_t)(row0+r)*CL + k0+kk];
    }
    int colB = tid & 63, kb = tid >> 6;
    #pragma unroll
    for (int q=0;q<4;q++){
      int kkb = kb + q*4;
      Bs[kkb][colB] = B[(size_t)(k0+kkb)*DD + col0+colB];
    }
    __syncthreads();
    #pragma unroll
    for (int kk2=0;kk2<16;kk2++){
      float a[4], b[4];
      #pragma unroll
      for (int m=0;m<4;m++) a[m] = As[kk2][ty*4+m];
      #pragma unroll
      for (int nn=0;nn<4;nn++) b[nn] = Bs[kk2][tx*4+nn];
      #pragma unroll
      for (int m=0;m<4;m++)
        #pragma unroll
        for (int nn=0;nn<4;nn++) acc[m][nn] += a[m]*b[nn];
    }
    __syncthreads();
  }
  #pragma unroll
  for (int m=0;m<4;m++){
    int row = row0 + ty*4+m;
    #pragma unroll
    for (int nn=0;nn<4;nn++){
      int col = col0 + tx*4+nn;
      Cc[(size_t)row*DD + col] = acc[m][nn];
    }
  }
}

// ---------------------------------------------------------------
// 5. A_head / A_tail concat staging
// ---------------------------------------------------------------
__global__ __launch_bounds__(256) void k_prepare_ab(const float* __restrict__ ent_emb,
    const float* __restrict__ rs, const int* __restrict__ hts,
    float* __restrict__ A_head, float* __restrict__ A_tail)
{
  int idx = blockIdx.x*256 + threadIdx.x;
  if (idx >= RTOT*1536) return;
  int kk = idx % 1536;
  int r  = idx / 1536;
  int doc = r / PP;
  int he = hts[r*2+0];
  int te = hts[r*2+1];
  float vh, vt;
  if (kk < DD){
    vh = ent_emb[(size_t)(doc*EE + he)*DD + kk];
    vt = ent_emb[(size_t)(doc*EE + te)*DD + kk];
  } else {
    float v = rs[(size_t)r*DD + (kk-DD)];
    vh = v; vt = v;
  }
  A_head[idx] = vh;
  A_tail[idx] = vt;
}

// ---------------------------------------------------------------
// 6. hs2 = tanh(A_head @ W_head + b_head); ts2 analogous
// ---------------------------------------------------------------
__global__ __launch_bounds__(256) void k_gemm_ht(
    const float* __restrict__ A_head, const float* __restrict__ A_tail,
    const float* __restrict__ W_head, const float* __restrict__ W_tail,
    const float* __restrict__ b_head, const float* __restrict__ b_tail,
    float* __restrict__ hs2, float* __restrict__ ts2)
{
  const int rt = blockIdx.x;
  const int ct = blockIdx.y;
  const int z  = blockIdx.z;
  const float* A    = z ? A_tail : A_head;
  const float* W    = z ? W_tail : W_head;
  const float* bias = z ? b_tail : b_head;
  float* Cc         = z ? ts2    : hs2;
  const int row0 = rt*64, col0 = ct*64;
  __shared__ float As[16][68];
  __shared__ float Bs[16][64];
  int tx = threadIdx.x, ty = threadIdx.y;
  int tid = ty*16 + tx;
  float acc[4][4] = {};
  for (int k0=0; k0<1536; k0+=16){
    int kk = tid & 15, rbase = tid >> 4;
    #pragma unroll
    for (int q=0;q<4;q++){
      int r = rbase + q*16;
      As[kk][r] = A[(size_t)(row0+r)*1536 + k0+kk];
    }
    int colB = tid & 63, kb = tid >> 6;
    #pragma unroll
    for (int q=0;q<4;q++){
      int kkb = kb + q*4;
      Bs[kkb][colB] = W[(size_t)(k0+kkb)*DD + col0+colB];
    }
    __syncthreads();
    #pragma unroll
    for (int kk2=0;kk2<16;kk2++){
      float a[4], b[4];
      #pragma unroll
      for (int m=0;m<4;m++) a[m] = As[kk2][ty*4+m];
      #pragma unroll
      for (int nn=0;nn<4;nn++) b[nn] = Bs[kk2][tx*4+nn];
      #pragma unroll
      for (int m=0;m<4;m++)
        #pragma unroll
        for (int nn=0;nn<4;nn++) acc[m][nn] += a[m]*b[nn];
    }
    __syncthreads();
  }
  #pragma unroll
  for (int m=0;m<4;m++){
    int row = row0 + ty*4+m;
    #pragma unroll
    for (int nn=0;nn<4;nn++){
      int col = col0 + tx*4+nn;
      Cc[(size_t)row*DD + col] = tanhf(acc[m][nn] + bias[col]);
    }
  }
}

// ---------------------------------------------------------------
// 6b. Wt2: chunked, transposed, padded bf16 image of W_bil.
//     chunk cc (32 K-rows): Wt2[cc*4480 + n*40 + kk] = bf16(W_bil[(cc*32+kk)*97 + n])
//     n in [0,112) (zero-padded beyond 97), kk in [0,40) (kk>=32 zero).
// ---------------------------------------------------------------
__global__ __launch_bounds__(256) void k_wt2(const float* __restrict__ W_bil,
    unsigned short* __restrict__ Wt2)
{
  const int cc = blockIdx.x;          // 0..1535
  __shared__ unsigned short lds2[4480];
  int tid = threadIdx.x;
  for (int u=tid; u<4480; u+=256) lds2[u] = 0;
  __syncthreads();
  for (int u=tid; u<112*32; u+=256){
    int kk = u / 112, n = u % 112;
    if (n < OUTD)
      lds2[n*40 + kk] = (unsigned short)f_to_bf16u(W_bil[(size_t)(cc*32 + kk)*OUTD + n]);
  }
  __syncthreads();
  uint4* dst = (uint4*)(Wt2 + (size_t)cc*4480);
  const uint4* src = (const uint4*)lds2;
  for (int v=tid; v<560; v+=256) dst[v] = src[v];
}

// ---------------------------------------------------------------
// 7a. logits init with bias
// ---------------------------------------------------------------
__global__ __launch_bounds__(256) void k_init_logits(const float* __restrict__ b_bil,
    float* __restrict__ out)
{
  int idx = blockIdx.x*256 + threadIdx.x;
  if (idx >= RTOT*OUTD) return;
  out[idx] = b_bil[idx % OUTD];
}

// ---------------------------------------------------------------
// 7b. bilinear via bf16 MFMA 16x16x32.
//     C[1024,97] = A[1024,49152] @ W, A[r,t] = hs2[r,kb*64+i]*ts2[r,kb*64+j],
//     t = kb*4096 + i*64 + j. A-fragments built in registers from LDS-staged
//     hs2 (fp32) and ts2 (bf16). B staged per 32-K chunk from Wt2.
//     grid (8 row-tiles of 128, 48 K-splits of 1024); fp32 atomic epilogue.
// ---------------------------------------------------------------
__global__ __launch_bounds__(256) void k_bilinear(
    const float* __restrict__ hs2, const float* __restrict__ ts2,
    const unsigned short* __restrict__ Wt2, float* __restrict__ logits)
{
  const int rt = blockIdx.x;          // 0..7   (128 rows each)
  const int sp = blockIdx.y;          // 0..47  (K range [sp*1024, +1024))
  const int kb = sp >> 2;             // 0..11
  const int i0 = (sp & 3) * 16;       // i base within this kb
  const int row0 = rt * 128;

  __shared__ __align__(16) float b1s[128][17];            // 8704 B
  __shared__ __align__(16) unsigned short b2s[128][72];   // 18432 B (cols 64..71 unused)
  __shared__ __align__(16) unsigned short Ws[4480];       // 8960 B  [n][40]

  const int tid = threadIdx.x;
  const int lane = tid & 63, wave = tid >> 6;
  const int m = lane & 15, j8 = lane >> 4;

  // stage b1 (fp32) and b2 (bf16) row slabs for this block
  for (int u=tid; u<128*16; u+=256){
    int r = u >> 4, ii = u & 15;
    b1s[r][ii] = hs2[(size_t)(row0+r)*EMBD + kb*64 + i0 + ii];
  }
  for (int u=tid; u<128*64; u+=256){
    int r = u >> 6, j = u & 63;
    b2s[r][j] = (unsigned short)f_to_bf16u(ts2[(size_t)(row0+r)*EMBD + kb*64 + j]);
  }

  const uint4* gsrc = (const uint4*)(Wt2 + (size_t)(sp*32)*4480);
  uint4* ws4 = (uint4*)Ws;
  uint4 pf0, pf1, pf2;
  {
    pf0 = gsrc[tid];
    pf1 = gsrc[tid+256];
    if (tid < 48) pf2 = gsrc[tid+512];
  }

  f32x4 acc[2][7];
  #pragma unroll
  for (int f=0;f<2;f++)
    #pragma unroll
    for (int nt=0;nt<7;nt++) acc[f][nt] = {0.f,0.f,0.f,0.f};

  for (int c=0; c<32; c++){
    __syncthreads();            // Ws consumers of previous chunk done (also covers b1s/b2s staging)
    ws4[tid] = pf0; ws4[tid+256] = pf1; if (tid < 48) ws4[tid+512] = pf2;
    if (c+1 < 32){
      size_t b = (size_t)(c+1)*560;
      pf0 = gsrc[b+tid];
      pf1 = gsrc[b+tid+256];
      if (tid < 48) pf2 = gsrc[b+tid+512];
    }
    __syncthreads();

    const int i_rel = c >> 1;
    const int j0 = (c & 1) * 32;

    short8 bfr[7];
    #pragma unroll
    for (int nt=0;nt<7;nt++)
      bfr[nt] = *(const short8*)&Ws[(nt*16 + m)*40 + j8*8];

    #pragma unroll
    for (int f=0;f<2;f++){
      int r = wave*32 + f*16 + m;
      float s = b1s[r][i_rel];
      uint4 u = *(const uint4*)&b2s[r][j0 + j8*8];
      unsigned uw[4] = {u.x, u.y, u.z, u.w};
      short8 af;
      #pragma unroll
      for (int e=0;e<4;e++){
        af[2*e]   = (short)f_to_bf16u(s * bf16u_to_f(uw[e] & 0xffffu));
        af[2*e+1] = (short)f_to_bf16u(s * bf16u_to_f(uw[e] >> 16));
      }
      #pragma unroll
      for (int nt=0;nt<7;nt++)
        acc[f][nt] = __builtin_amdgcn_mfma_f32_16x16x32_bf16(af, bfr[nt], acc[f][nt], 0, 0, 0);
    }
  }

  // epilogue: C/D layout col=lane&15, row=(lane>>4)*4+reg
  #pragma unroll
  for (int f=0;f<2;f++){
    #pragma unroll
    for (int nt=0;nt<7;nt++){
      int col = nt*16 + m;
      if (col < OUTD){
        #pragma unroll
        for (int reg=0;reg<4;reg++){
          int grow = row0 + wave*32 + f*16 + j8*4 + reg;
          atomicAdd(&logits[(size_t)grow*OUTD + col], acc[f][nt][reg]);
        }
      }
    }
  }
}

// ---------------------------------------------------------------
extern "C" void kernel_launch(void* const* d_in, const int* in_sizes, int n_in,
                              void* d_out, int out_size, void* d_ws, size_t ws_size,
                              hipStream_t stream)
{
  const float* seq    = (const float*)d_in[0];
  const float* attn   = (const float*)d_in[1];
  const int*   mpos   = (const int*)d_in[2];
  const int*   hts    = (const int*)d_in[3];
  const float* W_head = (const float*)d_in[4];
  const float* b_head = (const float*)d_in[5];
  const float* W_tail = (const float*)d_in[6];
  const float* b_tail = (const float*)d_in[7];
  const float* W_bil  = (const float*)d_in[8];
  const float* b_bil  = (const float*)d_in[9];
  float* logits = (float*)d_out;

  float* ws      = (float*)d_ws;
  float* ent_emb = ws;                                   // 98304
  float* ent_att = ent_emb + ND*EE*DD;                   // 1572864
  float* ht_att  = ent_att + (size_t)ND*EE*HH*CL;        // 1048576
  float* rs      = ht_att  + (size_t)ND*PP*CL;           // 786432
  float* A_head  = rs      + (size_t)RTOT*DD;            // 1572864
  float* A_tail  = A_head  + (size_t)RTOT*1536;          // 1572864
  float* hs2     = A_tail  + (size_t)RTOT*1536;          // 786432
  float* ts2     = hs2     + (size_t)RTOT*EMBD;          // 786432
  // Wt2 (13.76 MB of bf16) aliases rs+A_head+A_tail (15.7 MB), which are
  // dead after k_gemm_ht. 16-B aligned: rs offset = 2719744 floats.
  unsigned short* Wt2 = (unsigned short*)rs;

  k_ent_emb<<<(ND*EE*DD+255)/256, 256, 0, stream>>>(seq, mpos, ent_emb);
  k_ent_att<<<(ND*EE*HH*CL+255)/256, 256, 0, stream>>>(attn, mpos, ent_att);
  k_ht_att<<<ND*PP, 256, 0, stream>>>(ent_att, hts, ht_att);
  k_gemm_rs<<<dim3(PP/64, DD/64, ND), dim3(16,16), 0, stream>>>(ht_att, seq, rs);
  k_prepare_ab<<<(RTOT*1536+255)/256, 256, 0, stream>>>(ent_emb, rs, hts, A_head, A_tail);
  k_gemm_ht<<<dim3(RTOT/64, DD/64, 2), dim3(16,16), 0, stream>>>(
      A_head, A_tail, W_head, W_tail, b_head, b_tail, hs2, ts2);
  k_wt2<<<1536, 256, 0, stream>>>(W_bil, Wt2);
  k_init_logits<<<(RTOT*OUTD+255)/256, 256, 0, stream>>>(b_bil, logits);
  k_bilinear<<<dim3(RTOT/128, 48), 256, 0, stream>>>(hs2, ts2, Wt2, logits);
}

// Round 3
// 404.566 us; speedup vs baseline: 2.2821x; 1.3343x over previous
//
#include <hip/hip_runtime.h>
#include <hip/hip_bf16.h>
#include <math.h>

// Problem constants (from reference setup_inputs)
#define ND 4      // batch n
#define CL 1024   // sequence length c
#define DD 768    // hidden d
#define HH 12     // heads h
#define EE 32     // entities E
#define MMEN 4    // mentions M
#define PP 256    // pairs P
#define EMBD 768  // EMB
#define KBL 12    // K = EMB/BLOCK
#define OUTD 97   // output classes
#define RTOT (ND*PP)  // 1024 rows

typedef unsigned short u16;
typedef __attribute__((ext_vector_type(8))) short short8;
typedef __attribute__((ext_vector_type(4))) float f32x4;

static __device__ inline float bf16u_to_f(unsigned v){
  union { unsigned u; float f; } c; c.u = v << 16; return c.f;
}
static __device__ inline unsigned f_to_bf16u(float f){
  union { float f; unsigned u; } c; c.f = f;
  return (c.u + 0x7fffu + ((c.u >> 16) & 1u)) >> 16;
}

#define GLOAD_LDS16(gp, lp) __builtin_amdgcn_global_load_lds( \
    (const __attribute__((address_space(1))) unsigned*)(gp), \
    (__attribute__((address_space(3))) unsigned*)(lp), 16, 0, 0)

// ---------------------------------------------------------------
// 1. ent_emb_bf[i,e,dd] = bf16( logsumexp_m seq[i, mpos[i,e,m], dd] )
// ---------------------------------------------------------------
__global__ __launch_bounds__(256) void k_ent_emb(const float* __restrict__ seq,
    const int* __restrict__ mpos, u16* __restrict__ ent_emb_bf)
{
  int idx = blockIdx.x*256 + threadIdx.x;
  if (idx >= ND*EE*DD) return;
  int dd = idx % DD;
  int e  = (idx / DD) % EE;
  int i  = idx / (DD*EE);
  const int* mp = mpos + (i*EE + e)*MMEN;
  float v[MMEN];
  float mx = -1e30f;
  #pragma unroll
  for (int m=0;m<MMEN;m++){
    v[m] = seq[(i*CL + mp[m])*DD + dd];
    mx = fmaxf(mx, v[m]);
  }
  float s = 0.f;
  #pragma unroll
  for (int m=0;m<MMEN;m++) s += expf(v[m]-mx);
  ent_emb_bf[idx] = (u16)f_to_bf16u(mx + logf(s));
}

// ---------------------------------------------------------------
// 2. ent_att[i,e,head,j] = mean_m attn[i, head, mpos[i,e,m], j]
// ---------------------------------------------------------------
__global__ __launch_bounds__(256) void k_ent_att(const float* __restrict__ attn,
    const int* __restrict__ mpos, float* __restrict__ ent_att)
{
  int idx = blockIdx.x*256 + threadIdx.x;
  if (idx >= ND*EE*HH*CL) return;
  int j    = idx % CL;
  int head = (idx / CL) % HH;
  int e    = (idx / (CL*HH)) % EE;
  int i    = idx / (CL*HH*EE);
  const int* mp = mpos + (i*EE + e)*MMEN;
  float s = 0.f;
  #pragma unroll
  for (int m=0;m<MMEN;m++)
    s += attn[((size_t)(i*HH + head)*CL + mp[m])*CL + j];
  ent_att[idx] = s * (1.f/MMEN);
}

// ---------------------------------------------------------------
// 3. ht_att_bf[i,p,j] = bf16( normalize_j( mean_head ha*ta ) )
// ---------------------------------------------------------------
__global__ __launch_bounds__(256) void k_ht_att(const float* __restrict__ ent_att,
    const int* __restrict__ hts, u16* __restrict__ ht_att_bf)
{
  int bp = blockIdx.x;            // i*PP + p
  int i  = bp / PP;
  int tid = threadIdx.x;
  int he = hts[bp*2+0];
  int te = hts[bp*2+1];
  const float* ha = ent_att + ((size_t)(i*EE + he)*HH)*CL;
  const float* ta = ent_att + ((size_t)(i*EE + te)*HH)*CL;
  float v[4];
  #pragma unroll
  for (int q=0;q<4;q++){
    int j = tid + q*256;
    float s = 0.f;
    #pragma unroll
    for (int head=0; head<HH; head++)
      s += ha[head*CL + j] * ta[head*CL + j];
    v[q] = s * (1.f/HH);
  }
  float part = v[0]+v[1]+v[2]+v[3];
  #pragma unroll
  for (int off=32; off>0; off>>=1) part += __shfl_down(part, off, 64);
  __shared__ float wsum[4];
  __shared__ float tot_s;
  int lane = tid & 63, wv = tid >> 6;
  if (lane==0) wsum[wv] = part;
  __syncthreads();
  if (tid==0) tot_s = wsum[0]+wsum[1]+wsum[2]+wsum[3];
  __syncthreads();
  float inv = 1.f/(tot_s + 1e-30f);
  #pragma unroll
  for (int q=0;q<4;q++){
    int j = tid + q*256;
    ht_att_bf[(size_t)bp*CL + j] = (u16)f_to_bf16u(v[q]*inv);
  }
}

// ---------------------------------------------------------------
// 3b. transpose+convert: dst_bf16[C][R] = src_f32[R][C], batched over z
// ---------------------------------------------------------------
__global__ __launch_bounds__(256) void k_transpose_bf(const float* __restrict__ src,
    u16* __restrict__ dst, int R, int C)
{
  size_t boff = (size_t)blockIdx.z * R * C;
  src += boff; dst += boff;
  __shared__ float t[32][33];
  int tx = threadIdx.x & 31, ty = threadIdx.x >> 5;   // ty 0..7
  int c0 = blockIdx.x*32, r0 = blockIdx.y*32;
  #pragma unroll
  for (int q=0;q<4;q++)
    t[ty+8*q][tx] = src[(size_t)(r0+ty+8*q)*C + c0+tx];
  __syncthreads();
  #pragma unroll
  for (int q=0;q<4;q++)
    dst[(size_t)(c0+ty+8*q)*R + r0+tx] = (u16)f_to_bf16u(t[tx][ty+8*q]);
}

// ---------------------------------------------------------------
// 4. rs_bf[doc*256+p, dd] = bf16( sum_j ht_att[p,j] seq[j,dd] )  via MFMA.
//    A = ht_att_bf [doc][256][1024], Bt = seq_t_bf [doc][768][1024].
//    BM=128 BN=64 BK=32; grid (2, 12, 4).
// ---------------------------------------------------------------
__global__ __launch_bounds__(256) void k_gemm_rs_mfma(
    const u16* __restrict__ ht_att_bf, const u16* __restrict__ seq_t_bf,
    u16* __restrict__ rs_bf)
{
  const int rt = blockIdx.x, ct = blockIdx.y, doc = blockIdx.z;
  const u16* A  = ht_att_bf + (size_t)doc*PP*CL;
  const u16* Bt = seq_t_bf  + (size_t)doc*DD*CL;
  const int row0 = rt*128, col0 = ct*64;
  __shared__ __align__(16) u16 As[128*32];
  __shared__ __align__(16) u16 Bs[64*32];
  const int tid = threadIdx.x, lane = tid & 63, wave = tid >> 6;
  const int m = lane & 15, j8 = lane >> 4;
  const int srow = lane >> 2, schunk = lane & 3;
  f32x4 acc[2][4];
  #pragma unroll
  for (int a=0;a<2;a++)
    #pragma unroll
    for (int b=0;b<4;b++) acc[a][b] = (f32x4){0.f,0.f,0.f,0.f};

  for (int k0 = 0; k0 < CL; k0 += 32){
    __syncthreads();
    #pragma unroll
    for (int ii=0; ii<2; ii++){
      int i = wave*2 + ii;
      int row = i*16 + srow;
      int gc = schunk ^ ((row>>1)&3);
      const u16* gp = A + (size_t)(row0+row)*CL + k0 + gc*8;
      GLOAD_LDS16(gp, &As[i*16*32]);
    }
    {
      int row = wave*16 + srow;
      int gc = schunk ^ ((row>>1)&3);
      const u16* gp = Bt + (size_t)(col0+row)*CL + k0 + gc*8;
      GLOAD_LDS16(gp, &Bs[wave*16*32]);
    }
    __syncthreads();
    short8 af[2], bf[4];
    #pragma unroll
    for (int mf=0; mf<2; mf++){
      int r = wave*32 + mf*16 + m;
      af[mf] = *(const short8*)&As[r*32 + 8*(j8 ^ ((r>>1)&3))];
    }
    #pragma unroll
    for (int nt=0; nt<4; nt++){
      int n = nt*16 + m;
      bf[nt] = *(const short8*)&Bs[n*32 + 8*(j8 ^ ((n>>1)&3))];
    }
    #pragma unroll
    for (int mf=0; mf<2; mf++)
      #pragma unroll
      for (int nt=0; nt<4; nt++)
        acc[mf][nt] = __builtin_amdgcn_mfma_f32_16x16x32_bf16(af[mf], bf[nt], acc[mf][nt], 0,0,0);
  }

  #pragma unroll
  for (int mf=0; mf<2; mf++){
    #pragma unroll
    for (int nt=0; nt<4; nt++){
      int colg = col0 + nt*16 + m;
      #pragma unroll
      for (int reg=0; reg<4; reg++){
        int rowg = doc*PP + row0 + wave*32 + mf*16 + j8*4 + reg;
        rs_bf[(size_t)rowg*DD + colg] = (u16)f_to_bf16u(acc[mf][nt][reg]);
      }
    }
  }
}

// ---------------------------------------------------------------
// 5. A_head_bf / A_tail_bf concat gather (pure bf16 copies, uint4-wide)
// ---------------------------------------------------------------
__global__ __launch_bounds__(256) void k_prepare_ab(
    const u16* __restrict__ ent_emb_bf, const u16* __restrict__ rs_bf,
    const int* __restrict__ hts, uint4* __restrict__ Ah, uint4* __restrict__ At)
{
  int idx = blockIdx.x*256 + threadIdx.x;     // over RTOT*192 uint4
  if (idx >= RTOT*192) return;
  int g = idx % 192, r = idx / 192;
  int doc = r >> 8;
  int he = hts[r*2+0], te = hts[r*2+1];
  uint4 vh, vt;
  if (g < 96){
    vh = ((const uint4*)ent_emb_bf)[(size_t)(doc*EE+he)*96 + g];
    vt = ((const uint4*)ent_emb_bf)[(size_t)(doc*EE+te)*96 + g];
  } else {
    uint4 v = ((const uint4*)rs_bf)[(size_t)r*96 + (g-96)];
    vh = v; vt = v;
  }
  Ah[idx] = vh; At[idx] = vt;
}

// ---------------------------------------------------------------
// 6. hs2 = tanh(A_head @ W_head + b_head); ts2 analogous.  bf16 MFMA.
//    A [1024][1536], Bt = W^T [768][1536]. BM=128 BN=64 BK=32; grid (8,12,2).
// ---------------------------------------------------------------
__global__ __launch_bounds__(256) void k_gemm_ht_mfma(
    const u16* __restrict__ Ah, const u16* __restrict__ At,
    const u16* __restrict__ Wht, const u16* __restrict__ Wtt,
    const float* __restrict__ b_head, const float* __restrict__ b_tail,
    float* __restrict__ hs2, float* __restrict__ ts2)
{
  const int rt = blockIdx.x, ct = blockIdx.y, z = blockIdx.z;
  const u16* A    = z ? At  : Ah;
  const u16* Bt   = z ? Wtt : Wht;
  const float* bias = z ? b_tail : b_head;
  float* C        = z ? ts2 : hs2;
  const int row0 = rt*128, col0 = ct*64;
  __shared__ __align__(16) u16 As[128*32];
  __shared__ __align__(16) u16 Bs[64*32];
  const int tid = threadIdx.x, lane = tid & 63, wave = tid >> 6;
  const int m = lane & 15, j8 = lane >> 4;
  const int srow = lane >> 2, schunk = lane & 3;
  f32x4 acc[2][4];
  #pragma unroll
  for (int a=0;a<2;a++)
    #pragma unroll
    for (int b=0;b<4;b++) acc[a][b] = (f32x4){0.f,0.f,0.f,0.f};

  for (int k0 = 0; k0 < 1536; k0 += 32){
    __syncthreads();
    #pragma unroll
    for (int ii=0; ii<2; ii++){
      int i = wave*2 + ii;
      int row = i*16 + srow;
      int gc = schunk ^ ((row>>1)&3);
      const u16* gp = A + (size_t)(row0+row)*1536 + k0 + gc*8;
      GLOAD_LDS16(gp, &As[i*16*32]);
    }
    {
      int row = wave*16 + srow;
      int gc = schunk ^ ((row>>1)&3);
      const u16* gp = Bt + (size_t)(col0+row)*1536 + k0 + gc*8;
      GLOAD_LDS16(gp, &Bs[wave*16*32]);
    }
    __syncthreads();
    short8 af[2], bf[4];
    #pragma unroll
    for (int mf=0; mf<2; mf++){
      int r = wave*32 + mf*16 + m;
      af[mf] = *(const short8*)&As[r*32 + 8*(j8 ^ ((r>>1)&3))];
    }
    #pragma unroll
    for (int nt=0; nt<4; nt++){
      int n = nt*16 + m;
      bf[nt] = *(const short8*)&Bs[n*32 + 8*(j8 ^ ((n>>1)&3))];
    }
    #pragma unroll
    for (int mf=0; mf<2; mf++)
      #pragma unroll
      for (int nt=0; nt<4; nt++)
        acc[mf][nt] = __builtin_amdgcn_mfma_f32_16x16x32_bf16(af[mf], bf[nt], acc[mf][nt], 0,0,0);
  }

  #pragma unroll
  for (int mf=0; mf<2; mf++){
    #pragma unroll
    for (int nt=0; nt<4; nt++){
      int colg = col0 + nt*16 + m;
      float bv = bias[colg];
      #pragma unroll
      for (int reg=0; reg<4; reg++){
        int rowg = row0 + wave*32 + mf*16 + j8*4 + reg;
        C[(size_t)rowg*DD + colg] = tanhf(acc[mf][nt][reg] + bv);
      }
    }
  }
}

// ---------------------------------------------------------------
// 6b. Wt2: chunked, transposed, padded bf16 image of W_bil.
// ---------------------------------------------------------------
__global__ __launch_bounds__(256) void k_wt2(const float* __restrict__ W_bil,
    u16* __restrict__ Wt2)
{
  const int cc = blockIdx.x;          // 0..1535
  __shared__ u16 lds2[4480];
  int tid = threadIdx.x;
  for (int u=tid; u<4480; u+=256) lds2[u] = 0;
  __syncthreads();
  for (int u=tid; u<112*32; u+=256){
    int kk = u / 112, n = u % 112;
    if (n < OUTD)
      lds2[n*40 + kk] = (u16)f_to_bf16u(W_bil[(size_t)(cc*32 + kk)*OUTD + n]);
  }
  __syncthreads();
  uint4* dst = (uint4*)(Wt2 + (size_t)cc*4480);
  const uint4* src = (const uint4*)lds2;
  for (int v=tid; v<560; v+=256) dst[v] = src[v];
}

// ---------------------------------------------------------------
// 7a. logits init with bias
// ---------------------------------------------------------------
__global__ __launch_bounds__(256) void k_init_logits(const float* __restrict__ b_bil,
    float* __restrict__ out)
{
  int idx = blockIdx.x*256 + threadIdx.x;
  if (idx >= RTOT*OUTD) return;
  out[idx] = b_bil[idx % OUTD];
}

// ---------------------------------------------------------------
// 7b. bilinear via bf16 MFMA 16x16x32 (unchanged from round 1)
// ---------------------------------------------------------------
__global__ __launch_bounds__(256) void k_bilinear(
    const float* __restrict__ hs2, const float* __restrict__ ts2,
    const u16* __restrict__ Wt2, float* __restrict__ logits)
{
  const int rt = blockIdx.x;          // 0..7   (128 rows each)
  const int sp = blockIdx.y;          // 0..47  (K range [sp*1024, +1024))
  const int kb = sp >> 2;             // 0..11
  const int i0 = (sp & 3) * 16;       // i base within this kb
  const int row0 = rt * 128;

  __shared__ __align__(16) float b1s[128][17];
  __shared__ __align__(16) u16 b2s[128][72];
  __shared__ __align__(16) u16 Ws[4480];

  const int tid = threadIdx.x;
  const int lane = tid & 63, wave = tid >> 6;
  const int m = lane & 15, j8 = lane >> 4;

  for (int u=tid; u<128*16; u+=256){
    int r = u >> 4, ii = u & 15;
    b1s[r][ii] = hs2[(size_t)(row0+r)*EMBD + kb*64 + i0 + ii];
  }
  for (int u=tid; u<128*64; u+=256){
    int r = u >> 6, j = u & 63;
    b2s[r][j] = (u16)f_to_bf16u(ts2[(size_t)(row0+r)*EMBD + kb*64 + j]);
  }

  const uint4* gsrc = (const uint4*)(Wt2 + (size_t)(sp*32)*4480);
  uint4* ws4 = (uint4*)Ws;
  uint4 pf0, pf1, pf2;
  {
    pf0 = gsrc[tid];
    pf1 = gsrc[tid+256];
    if (tid < 48) pf2 = gsrc[tid+512];
  }

  f32x4 acc[2][7];
  #pragma unroll
  for (int f=0;f<2;f++)
    #pragma unroll
    for (int nt=0;nt<7;nt++) acc[f][nt] = (f32x4){0.f,0.f,0.f,0.f};

  for (int c=0; c<32; c++){
    __syncthreads();
    ws4[tid] = pf0; ws4[tid+256] = pf1; if (tid < 48) ws4[tid+512] = pf2;
    if (c+1 < 32){
      size_t b = (size_t)(c+1)*560;
      pf0 = gsrc[b+tid];
      pf1 = gsrc[b+tid+256];
      if (tid < 48) pf2 = gsrc[b+tid+512];
    }
    __syncthreads();

    const int i_rel = c >> 1;
    const int j0 = (c & 1) * 32;

    short8 bfr[7];
    #pragma unroll
    for (int nt=0;nt<7;nt++)
      bfr[nt] = *(const short8*)&Ws[(nt*16 + m)*40 + j8*8];

    #pragma unroll
    for (int f=0;f<2;f++){
      int r = wave*32 + f*16 + m;
      float s = b1s[r][i_rel];
      uint4 u = *(const uint4*)&b2s[r][j0 + j8*8];
      unsigned uw[4] = {u.x, u.y, u.z, u.w};
      short8 af;
      #pragma unroll
      for (int e=0;e<4;e++){
        af[2*e]   = (short)f_to_bf16u(s * bf16u_to_f(uw[e] & 0xffffu));
        af[2*e+1] = (short)f_to_bf16u(s * bf16u_to_f(uw[e] >> 16));
      }
      #pragma unroll
      for (int nt=0;nt<7;nt++)
        acc[f][nt] = __builtin_amdgcn_mfma_f32_16x16x32_bf16(af, bfr[nt], acc[f][nt], 0, 0, 0);
    }
  }

  #pragma unroll
  for (int f=0;f<2;f++){
    #pragma unroll
    for (int nt=0;nt<7;nt++){
      int col = nt*16 + m;
      if (col < OUTD){
        #pragma unroll
        for (int reg=0;reg<4;reg++){
          int grow = row0 + wave*32 + f*16 + j8*4 + reg;
          atomicAdd(&logits[(size_t)grow*OUTD + col], acc[f][nt][reg]);
        }
      }
    }
  }
}

// ---------------------------------------------------------------
extern "C" void kernel_launch(void* const* d_in, const int* in_sizes, int n_in,
                              void* d_out, int out_size, void* d_ws, size_t ws_size,
                              hipStream_t stream)
{
  const float* seq    = (const float*)d_in[0];
  const float* attn   = (const float*)d_in[1];
  const int*   mpos   = (const int*)d_in[2];
  const int*   hts    = (const int*)d_in[3];
  const float* W_head = (const float*)d_in[4];
  const float* b_head = (const float*)d_in[5];
  const float* W_tail = (const float*)d_in[6];
  const float* b_tail = (const float*)d_in[7];
  const float* W_bil  = (const float*)d_in[8];
  const float* b_bil  = (const float*)d_in[9];
  float* logits = (float*)d_out;

  float* ws = (float*)d_ws;
  // float-unit offsets (all 64-aligned)
  u16*   ent_emb_bf = (u16*)(ws + 0);          //  98304 u16
  u16*   rs_bf      = (u16*)(ws + 49152);      // 786432 u16
  float* hs2        = ws + 442368;             // 786432 f32
  float* ts2        = ws + 1228800;            // 786432 f32
  u16*   Wh_t       = (u16*)(ws + 2015232);    // 1179648 u16
  u16*   Wt_t       = (u16*)(ws + 2605056);    // 1179648 u16
  u16*   Ah_bf      = (u16*)(ws + 3194880);    // 1572864 u16
  u16*   At_bf      = (u16*)(ws + 3981312);    // 1572864 u16
  float* ent_att    = ws + 4767744;            // 1572864 f32  [dead after ht_att]
  u16*   seq_t_bf   = (u16*)(ws + 6340608);    // 3145728 u16  [dead after gemm_rs]
  u16*   ht_att_bf  = (u16*)(ws + 7913472);    // 1048576 u16  [dead after gemm_rs]
  // Wt2 (6881280 u16) aliases [ent_att | seq_t_bf | ht_att_bf] (7340032 u16 capacity)
  u16*   Wt2        = (u16*)(ws + 4767744);
  // total ws: 8437760 floats = 32.2 MiB

  k_ent_emb<<<(ND*EE*DD+255)/256, 256, 0, stream>>>(seq, mpos, ent_emb_bf);
  k_ent_att<<<(ND*EE*HH*CL+255)/256, 256, 0, stream>>>(attn, mpos, ent_att);
  k_ht_att<<<ND*PP, 256, 0, stream>>>(ent_att, hts, ht_att_bf);
  k_transpose_bf<<<dim3(DD/32, CL/32, ND), 256, 0, stream>>>(seq, seq_t_bf, CL, DD);
  k_transpose_bf<<<dim3(DD/32, 1536/32, 1), 256, 0, stream>>>(W_head, Wh_t, 1536, DD);
  k_transpose_bf<<<dim3(DD/32, 1536/32, 1), 256, 0, stream>>>(W_tail, Wt_t, 1536, DD);
  k_gemm_rs_mfma<<<dim3(2, 12, 4), 256, 0, stream>>>(ht_att_bf, seq_t_bf, rs_bf);
  k_prepare_ab<<<(RTOT*192+255)/256, 256, 0, stream>>>(ent_emb_bf, rs_bf, hts,
      (uint4*)Ah_bf, (uint4*)At_bf);
  k_gemm_ht_mfma<<<dim3(8, 12, 2), 256, 0, stream>>>(Ah_bf, At_bf, Wh_t, Wt_t,
      b_head, b_tail, hs2, ts2);
  k_wt2<<<1536, 256, 0, stream>>>(W_bil, Wt2);
  k_init_logits<<<(RTOT*OUTD+255)/256, 256, 0, stream>>>(b_bil, logits);
  k_bilinear<<<dim3(RTOT/128, 48), 256, 0, stream>>>(hs2, ts2, Wt2, logits);
}

// Round 4
// 377.421 us; speedup vs baseline: 2.4463x; 1.0719x over previous
//
#include <hip/hip_runtime.h>
#include <hip/hip_bf16.h>
#include <math.h>

// Problem constants (from reference setup_inputs)
#define ND 4      // batch n
#define CL 1024   // sequence length c
#define DD 768    // hidden d
#define HH 12     // heads h
#define EE 32     // entities E
#define MMEN 4    // mentions M
#define PP 256    // pairs P
#define EMBD 768  // EMB
#define KBL 12    // K = EMB/BLOCK
#define OUTD 97   // output classes
#define RTOT (ND*PP)  // 1024 rows
#define NSPLIT 48     // bilinear split-K factor

typedef unsigned short u16;
typedef __attribute__((ext_vector_type(8))) short short8;
typedef __attribute__((ext_vector_type(4))) float f32x4;

static __device__ inline float bf16u_to_f(unsigned v){
  union { unsigned u; float f; } c; c.u = v << 16; return c.f;
}
static __device__ inline unsigned f_to_bf16u(float f){
  union { float f; unsigned u; } c; c.f = f;
  return (c.u + 0x7fffu + ((c.u >> 16) & 1u)) >> 16;
}

#define GLOAD_LDS16(gp, lp) __builtin_amdgcn_global_load_lds( \
    (const __attribute__((address_space(1))) unsigned*)(gp), \
    (__attribute__((address_space(3))) unsigned*)(lp), 16, 0, 0)

// ---------------------------------------------------------------
// 1. ent_emb_bf[i,e,dd] = bf16( logsumexp_m seq[i, mpos[i,e,m], dd] )
// ---------------------------------------------------------------
__global__ __launch_bounds__(256) void k_ent_emb(const float* __restrict__ seq,
    const int* __restrict__ mpos, u16* __restrict__ ent_emb_bf)
{
  int idx = blockIdx.x*256 + threadIdx.x;
  if (idx >= ND*EE*DD) return;
  int dd = idx % DD;
  int e  = (idx / DD) % EE;
  int i  = idx / (DD*EE);
  const int* mp = mpos + (i*EE + e)*MMEN;
  float v[MMEN];
  float mx = -1e30f;
  #pragma unroll
  for (int m=0;m<MMEN;m++){
    v[m] = seq[(i*CL + mp[m])*DD + dd];
    mx = fmaxf(mx, v[m]);
  }
  float s = 0.f;
  #pragma unroll
  for (int m=0;m<MMEN;m++) s += expf(v[m]-mx);
  ent_emb_bf[idx] = (u16)f_to_bf16u(mx + logf(s));
}

// ---------------------------------------------------------------
// 2. ent_att[i,e,head,j] = mean_m attn[i, head, mpos[i,e,m], j]
// ---------------------------------------------------------------
__global__ __launch_bounds__(256) void k_ent_att(const float* __restrict__ attn,
    const int* __restrict__ mpos, float* __restrict__ ent_att)
{
  int idx = blockIdx.x*256 + threadIdx.x;
  if (idx >= ND*EE*HH*CL) return;
  int j    = idx % CL;
  int head = (idx / CL) % HH;
  int e    = (idx / (CL*HH)) % EE;
  int i    = idx / (CL*HH*EE);
  const int* mp = mpos + (i*EE + e)*MMEN;
  float s = 0.f;
  #pragma unroll
  for (int m=0;m<MMEN;m++)
    s += attn[((size_t)(i*HH + head)*CL + mp[m])*CL + j];
  ent_att[idx] = s * (1.f/MMEN);
}

// ---------------------------------------------------------------
// 3. ht_att_bf[i,p,j] = bf16( normalize_j( mean_head ha*ta ) )
// ---------------------------------------------------------------
__global__ __launch_bounds__(256) void k_ht_att(const float* __restrict__ ent_att,
    const int* __restrict__ hts, u16* __restrict__ ht_att_bf)
{
  int bp = blockIdx.x;            // i*PP + p
  int i  = bp / PP;
  int tid = threadIdx.x;
  int he = hts[bp*2+0];
  int te = hts[bp*2+1];
  const float* ha = ent_att + ((size_t)(i*EE + he)*HH)*CL;
  const float* ta = ent_att + ((size_t)(i*EE + te)*HH)*CL;
  float v[4];
  #pragma unroll
  for (int q=0;q<4;q++){
    int j = tid + q*256;
    float s = 0.f;
    #pragma unroll
    for (int head=0; head<HH; head++)
      s += ha[head*CL + j] * ta[head*CL + j];
    v[q] = s * (1.f/HH);
  }
  float part = v[0]+v[1]+v[2]+v[3];
  #pragma unroll
  for (int off=32; off>0; off>>=1) part += __shfl_down(part, off, 64);
  __shared__ float wsum[4];
  __shared__ float tot_s;
  int lane = tid & 63, wv = tid >> 6;
  if (lane==0) wsum[wv] = part;
  __syncthreads();
  if (tid==0) tot_s = wsum[0]+wsum[1]+wsum[2]+wsum[3];
  __syncthreads();
  float inv = 1.f/(tot_s + 1e-30f);
  #pragma unroll
  for (int q=0;q<4;q++){
    int j = tid + q*256;
    ht_att_bf[(size_t)bp*CL + j] = (u16)f_to_bf16u(v[q]*inv);
  }
}

// ---------------------------------------------------------------
// 3b. transpose+convert: dst_bf16[C][R] = src_f32[R][C], batched over z
// ---------------------------------------------------------------
__global__ __launch_bounds__(256) void k_transpose_bf(const float* __restrict__ src,
    u16* __restrict__ dst, int R, int C)
{
  size_t boff = (size_t)blockIdx.z * R * C;
  src += boff; dst += boff;
  __shared__ float t[32][33];
  int tx = threadIdx.x & 31, ty = threadIdx.x >> 5;   // ty 0..7
  int c0 = blockIdx.x*32, r0 = blockIdx.y*32;
  #pragma unroll
  for (int q=0;q<4;q++)
    t[ty+8*q][tx] = src[(size_t)(r0+ty+8*q)*C + c0+tx];
  __syncthreads();
  #pragma unroll
  for (int q=0;q<4;q++)
    dst[(size_t)(c0+ty+8*q)*R + r0+tx] = (u16)f_to_bf16u(t[tx][ty+8*q]);
}

// 3c. same, but src/dst selected by blockIdx.z (for W_head / W_tail)
__global__ __launch_bounds__(256) void k_transpose_bf_w(
    const float* __restrict__ srcA, u16* __restrict__ dstA,
    const float* __restrict__ srcB, u16* __restrict__ dstB, int R, int C)
{
  const float* src = blockIdx.z ? srcB : srcA;
  u16* dst         = blockIdx.z ? dstB : dstA;
  __shared__ float t[32][33];
  int tx = threadIdx.x & 31, ty = threadIdx.x >> 5;
  int c0 = blockIdx.x*32, r0 = blockIdx.y*32;
  #pragma unroll
  for (int q=0;q<4;q++)
    t[ty+8*q][tx] = src[(size_t)(r0+ty+8*q)*C + c0+tx];
  __syncthreads();
  #pragma unroll
  for (int q=0;q<4;q++)
    dst[(size_t)(c0+ty+8*q)*R + r0+tx] = (u16)f_to_bf16u(t[tx][ty+8*q]);
}

// ---------------------------------------------------------------
// 4. rs_bf = bf16( ht_att @ seq ) via MFMA. BM=128 BN=64 BK=32; grid (2,12,4)
// ---------------------------------------------------------------
__global__ __launch_bounds__(256) void k_gemm_rs_mfma(
    const u16* __restrict__ ht_att_bf, const u16* __restrict__ seq_t_bf,
    u16* __restrict__ rs_bf)
{
  const int rt = blockIdx.x, ct = blockIdx.y, doc = blockIdx.z;
  const u16* A  = ht_att_bf + (size_t)doc*PP*CL;
  const u16* Bt = seq_t_bf  + (size_t)doc*DD*CL;
  const int row0 = rt*128, col0 = ct*64;
  __shared__ __align__(16) u16 As[128*32];
  __shared__ __align__(16) u16 Bs[64*32];
  const int tid = threadIdx.x, lane = tid & 63, wave = tid >> 6;
  const int m = lane & 15, j8 = lane >> 4;
  const int srow = lane >> 2, schunk = lane & 3;
  f32x4 acc[2][4];
  #pragma unroll
  for (int a=0;a<2;a++)
    #pragma unroll
    for (int b=0;b<4;b++) acc[a][b] = (f32x4){0.f,0.f,0.f,0.f};

  for (int k0 = 0; k0 < CL; k0 += 32){
    __syncthreads();
    #pragma unroll
    for (int ii=0; ii<2; ii++){
      int i = wave*2 + ii;
      int row = i*16 + srow;
      int gc = schunk ^ ((row>>1)&3);
      const u16* gp = A + (size_t)(row0+row)*CL + k0 + gc*8;
      GLOAD_LDS16(gp, &As[i*16*32]);
    }
    {
      int row = wave*16 + srow;
      int gc = schunk ^ ((row>>1)&3);
      const u16* gp = Bt + (size_t)(col0+row)*CL + k0 + gc*8;
      GLOAD_LDS16(gp, &Bs[wave*16*32]);
    }
    __syncthreads();
    short8 af[2], bf[4];
    #pragma unroll
    for (int mf=0; mf<2; mf++){
      int r = wave*32 + mf*16 + m;
      af[mf] = *(const short8*)&As[r*32 + 8*(j8 ^ ((r>>1)&3))];
    }
    #pragma unroll
    for (int nt=0; nt<4; nt++){
      int n = nt*16 + m;
      bf[nt] = *(const short8*)&Bs[n*32 + 8*(j8 ^ ((n>>1)&3))];
    }
    #pragma unroll
    for (int mf=0; mf<2; mf++)
      #pragma unroll
      for (int nt=0; nt<4; nt++)
        acc[mf][nt] = __builtin_amdgcn_mfma_f32_16x16x32_bf16(af[mf], bf[nt], acc[mf][nt], 0,0,0);
  }

  #pragma unroll
  for (int mf=0; mf<2; mf++){
    #pragma unroll
    for (int nt=0; nt<4; nt++){
      int colg = col0 + nt*16 + m;
      #pragma unroll
      for (int reg=0; reg<4; reg++){
        int rowg = doc*PP + row0 + wave*32 + mf*16 + j8*4 + reg;
        rs_bf[(size_t)rowg*DD + colg] = (u16)f_to_bf16u(acc[mf][nt][reg]);
      }
    }
  }
}

// ---------------------------------------------------------------
// 5. A_head_bf / A_tail_bf concat gather (uint4-wide)
// ---------------------------------------------------------------
__global__ __launch_bounds__(256) void k_prepare_ab(
    const u16* __restrict__ ent_emb_bf, const u16* __restrict__ rs_bf,
    const int* __restrict__ hts, uint4* __restrict__ Ah, uint4* __restrict__ At)
{
  int idx = blockIdx.x*256 + threadIdx.x;     // over RTOT*192 uint4
  if (idx >= RTOT*192) return;
  int g = idx % 192, r = idx / 192;
  int doc = r >> 8;
  int he = hts[r*2+0], te = hts[r*2+1];
  uint4 vh, vt;
  if (g < 96){
    vh = ((const uint4*)ent_emb_bf)[(size_t)(doc*EE+he)*96 + g];
    vt = ((const uint4*)ent_emb_bf)[(size_t)(doc*EE+te)*96 + g];
  } else {
    uint4 v = ((const uint4*)rs_bf)[(size_t)r*96 + (g-96)];
    vh = v; vt = v;
  }
  Ah[idx] = vh; At[idx] = vt;
}

// ---------------------------------------------------------------
// 6. hs2 = tanh(A_head @ W_head + b_head); ts2 analogous.  bf16 MFMA.
// ---------------------------------------------------------------
__global__ __launch_bounds__(256) void k_gemm_ht_mfma(
    const u16* __restrict__ Ah, const u16* __restrict__ At,
    const u16* __restrict__ Wht, const u16* __restrict__ Wtt,
    const float* __restrict__ b_head, const float* __restrict__ b_tail,
    float* __restrict__ hs2, float* __restrict__ ts2)
{
  const int rt = blockIdx.x, ct = blockIdx.y, z = blockIdx.z;
  const u16* A    = z ? At  : Ah;
  const u16* Bt   = z ? Wtt : Wht;
  const float* bias = z ? b_tail : b_head;
  float* C        = z ? ts2 : hs2;
  const int row0 = rt*128, col0 = ct*64;
  __shared__ __align__(16) u16 As[128*32];
  __shared__ __align__(16) u16 Bs[64*32];
  const int tid = threadIdx.x, lane = tid & 63, wave = tid >> 6;
  const int m = lane & 15, j8 = lane >> 4;
  const int srow = lane >> 2, schunk = lane & 3;
  f32x4 acc[2][4];
  #pragma unroll
  for (int a=0;a<2;a++)
    #pragma unroll
    for (int b=0;b<4;b++) acc[a][b] = (f32x4){0.f,0.f,0.f,0.f};

  for (int k0 = 0; k0 < 1536; k0 += 32){
    __syncthreads();
    #pragma unroll
    for (int ii=0; ii<2; ii++){
      int i = wave*2 + ii;
      int row = i*16 + srow;
      int gc = schunk ^ ((row>>1)&3);
      const u16* gp = A + (size_t)(row0+row)*1536 + k0 + gc*8;
      GLOAD_LDS16(gp, &As[i*16*32]);
    }
    {
      int row = wave*16 + srow;
      int gc = schunk ^ ((row>>1)&3);
      const u16* gp = Bt + (size_t)(col0+row)*1536 + k0 + gc*8;
      GLOAD_LDS16(gp, &Bs[wave*16*32]);
    }
    __syncthreads();
    short8 af[2], bf[4];
    #pragma unroll
    for (int mf=0; mf<2; mf++){
      int r = wave*32 + mf*16 + m;
      af[mf] = *(const short8*)&As[r*32 + 8*(j8 ^ ((r>>1)&3))];
    }
    #pragma unroll
    for (int nt=0; nt<4; nt++){
      int n = nt*16 + m;
      bf[nt] = *(const short8*)&Bs[n*32 + 8*(j8 ^ ((n>>1)&3))];
    }
    #pragma unroll
    for (int mf=0; mf<2; mf++)
      #pragma unroll
      for (int nt=0; nt<4; nt++)
        acc[mf][nt] = __builtin_amdgcn_mfma_f32_16x16x32_bf16(af[mf], bf[nt], acc[mf][nt], 0,0,0);
  }

  #pragma unroll
  for (int mf=0; mf<2; mf++){
    #pragma unroll
    for (int nt=0; nt<4; nt++){
      int colg = col0 + nt*16 + m;
      float bv = bias[colg];
      #pragma unroll
      for (int reg=0; reg<4; reg++){
        int rowg = row0 + wave*32 + mf*16 + j8*4 + reg;
        C[(size_t)rowg*DD + colg] = tanhf(acc[mf][nt][reg] + bv);
      }
    }
  }
}

// ---------------------------------------------------------------
// 6b. Wt2: chunked, transposed, padded bf16 image of W_bil.
// ---------------------------------------------------------------
__global__ __launch_bounds__(256) void k_wt2(const float* __restrict__ W_bil,
    u16* __restrict__ Wt2)
{
  const int cc = blockIdx.x;          // 0..1535
  __shared__ u16 lds2[4480];
  int tid = threadIdx.x;
  for (int u=tid; u<4480; u+=256) lds2[u] = 0;
  __syncthreads();
  for (int u=tid; u<112*32; u+=256){
    int kk = u / 112, n = u % 112;
    if (n < OUTD)
      lds2[n*40 + kk] = (u16)f_to_bf16u(W_bil[(size_t)(cc*32 + kk)*OUTD + n]);
  }
  __syncthreads();
  uint4* dst = (uint4*)(Wt2 + (size_t)cc*4480);
  const uint4* src = (const uint4*)lds2;
  for (int v=tid; v<560; v+=256) dst[v] = src[v];
}

// ---------------------------------------------------------------
// 7. bilinear via bf16 MFMA 16x16x32; atomic-free split-K:
//    each block stores its partial [128 rows x 112 cols] tile to
//    pbuf[sp][1024][112] with plain coalesced stores.
// ---------------------------------------------------------------
__global__ __launch_bounds__(256) void k_bilinear(
    const float* __restrict__ hs2, const float* __restrict__ ts2,
    const u16* __restrict__ Wt2, float* __restrict__ pbuf)
{
  const int rt = blockIdx.x;          // 0..7   (128 rows each)
  const int sp = blockIdx.y;          // 0..47  (K range [sp*1024, +1024))
  const int kb = sp >> 2;             // 0..11
  const int i0 = (sp & 3) * 16;       // i base within this kb
  const int row0 = rt * 128;

  __shared__ __align__(16) float b1s[128][17];
  __shared__ __align__(16) u16 b2s[128][72];
  __shared__ __align__(16) u16 Ws[4480];

  const int tid = threadIdx.x;
  const int lane = tid & 63, wave = tid >> 6;
  const int m = lane & 15, j8 = lane >> 4;

  for (int u=tid; u<128*16; u+=256){
    int r = u >> 4, ii = u & 15;
    b1s[r][ii] = hs2[(size_t)(row0+r)*EMBD + kb*64 + i0 + ii];
  }
  for (int u=tid; u<128*64; u+=256){
    int r = u >> 6, j = u & 63;
    b2s[r][j] = (u16)f_to_bf16u(ts2[(size_t)(row0+r)*EMBD + kb*64 + j]);
  }

  const uint4* gsrc = (const uint4*)(Wt2 + (size_t)(sp*32)*4480);
  uint4* ws4 = (uint4*)Ws;
  uint4 pf0, pf1, pf2;
  {
    pf0 = gsrc[tid];
    pf1 = gsrc[tid+256];
    if (tid < 48) pf2 = gsrc[tid+512];
  }

  f32x4 acc[2][7];
  #pragma unroll
  for (int f=0;f<2;f++)
    #pragma unroll
    for (int nt=0;nt<7;nt++) acc[f][nt] = (f32x4){0.f,0.f,0.f,0.f};

  for (int c=0; c<32; c++){
    __syncthreads();
    ws4[tid] = pf0; ws4[tid+256] = pf1; if (tid < 48) ws4[tid+512] = pf2;
    if (c+1 < 32){
      size_t b = (size_t)(c+1)*560;
      pf0 = gsrc[b+tid];
      pf1 = gsrc[b+tid+256];
      if (tid < 48) pf2 = gsrc[b+tid+512];
    }
    __syncthreads();

    const int i_rel = c >> 1;
    const int j0 = (c & 1) * 32;

    short8 bfr[7];
    #pragma unroll
    for (int nt=0;nt<7;nt++)
      bfr[nt] = *(const short8*)&Ws[(nt*16 + m)*40 + j8*8];

    #pragma unroll
    for (int f=0;f<2;f++){
      int r = wave*32 + f*16 + m;
      float s = b1s[r][i_rel];
      uint4 u = *(const uint4*)&b2s[r][j0 + j8*8];
      unsigned uw[4] = {u.x, u.y, u.z, u.w};
      short8 af;
      #pragma unroll
      for (int e=0;e<4;e++){
        af[2*e]   = (short)f_to_bf16u(s * bf16u_to_f(uw[e] & 0xffffu));
        af[2*e+1] = (short)f_to_bf16u(s * bf16u_to_f(uw[e] >> 16));
      }
      #pragma unroll
      for (int nt=0;nt<7;nt++)
        acc[f][nt] = __builtin_amdgcn_mfma_f32_16x16x32_bf16(af, bfr[nt], acc[f][nt], 0, 0, 0);
    }
  }

  // epilogue: plain stores to partial buffer (no atomics)
  float* dst = pbuf + ((size_t)sp*RTOT + row0)*112;
  #pragma unroll
  for (int f=0;f<2;f++){
    #pragma unroll
    for (int nt=0;nt<7;nt++){
      int col = nt*16 + m;
      #pragma unroll
      for (int reg=0;reg<4;reg++){
        int lrow = wave*32 + f*16 + j8*4 + reg;
        dst[(size_t)lrow*112 + col] = acc[f][nt][reg];
      }
    }
  }
}

// ---------------------------------------------------------------
// 8. reduce partials + bias -> logits
// ---------------------------------------------------------------
__global__ __launch_bounds__(256) void k_reduce_logits(
    const float* __restrict__ pbuf, const float* __restrict__ b_bil,
    float* __restrict__ logits)
{
  int idx = blockIdx.x*256 + threadIdx.x;   // over RTOT*112
  if (idx >= RTOT*112) return;
  int col = idx % 112, row = idx / 112;
  if (col >= OUTD) return;
  float s0 = 0.f, s1 = 0.f, s2 = 0.f, s3 = 0.f;
  const size_t stride = (size_t)RTOT*112;
  #pragma unroll
  for (int sp=0; sp<NSPLIT; sp+=4){
    s0 += pbuf[(sp+0)*stride + idx];
    s1 += pbuf[(sp+1)*stride + idx];
    s2 += pbuf[(sp+2)*stride + idx];
    s3 += pbuf[(sp+3)*stride + idx];
  }
  logits[(size_t)row*OUTD + col] = (s0+s1) + (s2+s3) + b_bil[col];
}

// ---------------------------------------------------------------
extern "C" void kernel_launch(void* const* d_in, const int* in_sizes, int n_in,
                              void* d_out, int out_size, void* d_ws, size_t ws_size,
                              hipStream_t stream)
{
  const float* seq    = (const float*)d_in[0];
  const float* attn   = (const float*)d_in[1];
  const int*   mpos   = (const int*)d_in[2];
  const int*   hts    = (const int*)d_in[3];
  const float* W_head = (const float*)d_in[4];
  const float* b_head = (const float*)d_in[5];
  const float* W_tail = (const float*)d_in[6];
  const float* b_tail = (const float*)d_in[7];
  const float* W_bil  = (const float*)d_in[8];
  const float* b_bil  = (const float*)d_in[9];
  float* logits = (float*)d_out;

  float* ws = (float*)d_ws;
  // float-unit offsets (all 64-aligned)
  u16*   ent_emb_bf = (u16*)(ws + 0);          //  98304 u16
  u16*   rs_bf      = (u16*)(ws + 49152);      // 786432 u16
  float* hs2        = ws + 442368;             // 786432 f32
  float* ts2        = ws + 1228800;            // 786432 f32
  u16*   Wh_t       = (u16*)(ws + 2015232);    // 1179648 u16
  u16*   Wt_t       = (u16*)(ws + 2605056);    // 1179648 u16
  u16*   Ah_bf      = (u16*)(ws + 3194880);    // 1572864 u16
  u16*   At_bf      = (u16*)(ws + 3981312);    // 1572864 u16
  float* ent_att    = ws + 4767744;            // 1572864 f32  [dead after ht_att]
  u16*   seq_t_bf   = (u16*)(ws + 6340608);    // 3145728 u16  [dead after gemm_rs]
  u16*   ht_att_bf  = (u16*)(ws + 7913472);    // 1048576 u16  [dead after gemm_rs]
  // Wt2 (6881280 u16) aliases [ent_att | seq_t_bf | ht_att_bf]
  u16*   Wt2        = (u16*)(ws + 4767744);
  float* pbuf       = ws + 8437760;            // 48*1024*112 = 5505024 f32
  // total ws: 13,942,784 floats = 53.2 MiB

  k_ent_emb<<<(ND*EE*DD+255)/256, 256, 0, stream>>>(seq, mpos, ent_emb_bf);
  k_ent_att<<<(ND*EE*HH*CL+255)/256, 256, 0, stream>>>(attn, mpos, ent_att);
  k_ht_att<<<ND*PP, 256, 0, stream>>>(ent_att, hts, ht_att_bf);
  k_transpose_bf<<<dim3(DD/32, CL/32, ND), 256, 0, stream>>>(seq, seq_t_bf, CL, DD);
  k_transpose_bf_w<<<dim3(DD/32, 1536/32, 2), 256, 0, stream>>>(
      W_head, Wh_t, W_tail, Wt_t, 1536, DD);
  k_gemm_rs_mfma<<<dim3(2, 12, 4), 256, 0, stream>>>(ht_att_bf, seq_t_bf, rs_bf);
  k_prepare_ab<<<(RTOT*192+255)/256, 256, 0, stream>>>(ent_emb_bf, rs_bf, hts,
      (uint4*)Ah_bf, (uint4*)At_bf);
  k_gemm_ht_mfma<<<dim3(8, 12, 2), 256, 0, stream>>>(Ah_bf, At_bf, Wh_t, Wt_t,
      b_head, b_tail, hs2, ts2);
  k_wt2<<<1536, 256, 0, stream>>>(W_bil, Wt2);
  k_bilinear<<<dim3(RTOT/128, NSPLIT), 256, 0, stream>>>(hs2, ts2, Wt2, pbuf);
  k_reduce_logits<<<(RTOT*112+255)/256, 256, 0, stream>>>(pbuf, b_bil, logits);
}

// Round 5
// 367.873 us; speedup vs baseline: 2.5098x; 1.0260x over previous
//
#include <hip/hip_runtime.h>
#include <hip/hip_bf16.h>
#include <math.h>

// Problem constants (from reference setup_inputs)
#define ND 4      // batch n
#define CL 1024   // sequence length c
#define DD 768    // hidden d
#define HH 12     // heads h
#define EE 32     // entities E
#define MMEN 4    // mentions M
#define PP 256    // pairs P
#define EMBD 768  // EMB
#define KBL 12    // K = EMB/BLOCK
#define OUTD 97   // output classes
#define RTOT (ND*PP)  // 1024 rows
#define NSPLIT 48     // bilinear split-K factor

typedef unsigned short u16;
typedef __attribute__((ext_vector_type(8))) short short8;
typedef __attribute__((ext_vector_type(4))) float f32x4;

static __device__ inline float bf16u_to_f(unsigned v){
  union { unsigned u; float f; } c; c.u = v << 16; return c.f;
}
static __device__ inline unsigned f_to_bf16u(float f){
  union { float f; unsigned u; } c; c.f = f;
  return (c.u + 0x7fffu + ((c.u >> 16) & 1u)) >> 16;
}

#define GLOAD_LDS16(gp, lp) __builtin_amdgcn_global_load_lds( \
    (const __attribute__((address_space(1))) unsigned*)(gp), \
    (__attribute__((address_space(3))) unsigned*)(lp), 16, 0, 0)

// ---------------------------------------------------------------
// 1. ent_emb_bf[i,e,dd] = bf16( logsumexp_m seq[i, mpos[i,e,m], dd] )
//    also zeroes S[1024] (pair row-sum accumulator used by k_ht_att)
// ---------------------------------------------------------------
__global__ __launch_bounds__(256) void k_ent_emb(const float* __restrict__ seq,
    const int* __restrict__ mpos, u16* __restrict__ ent_emb_bf,
    float* __restrict__ S)
{
  int idx = blockIdx.x*256 + threadIdx.x;
  if (idx >= ND*EE*DD) return;
  if (idx < RTOT) S[idx] = 0.f;
  int dd = idx % DD;
  int e  = (idx / DD) % EE;
  int i  = idx / (DD*EE);
  const int* mp = mpos + (i*EE + e)*MMEN;
  float v[MMEN];
  float mx = -1e30f;
  #pragma unroll
  for (int m=0;m<MMEN;m++){
    v[m] = seq[(i*CL + mp[m])*DD + dd];
    mx = fmaxf(mx, v[m]);
  }
  float s = 0.f;
  #pragma unroll
  for (int m=0;m<MMEN;m++) s += expf(v[m]-mx);
  ent_emb_bf[idx] = (u16)f_to_bf16u(mx + logf(s));
}

// ---------------------------------------------------------------
// 2. ent_att_bf[i,e,head,j] = bf16( mean_m attn[i, head, mpos[i,e,m], j] )
//    vectorized: one thread per 8 j
// ---------------------------------------------------------------
__global__ __launch_bounds__(256) void k_ent_att(const float* __restrict__ attn,
    const int* __restrict__ mpos, u16* __restrict__ ent_att_bf)
{
  int idx = blockIdx.x*256 + threadIdx.x;     // over ND*EE*HH*(CL/8)
  if (idx >= ND*EE*HH*(CL/8)) return;
  int j8   = idx % (CL/8);
  int head = (idx / (CL/8)) % HH;
  int e    = (idx / (CL/8*HH)) % EE;
  int i    = idx / (CL/8*HH*EE);
  const int* mp = mpos + (i*EE + e)*MMEN;
  float acc[8] = {};
  #pragma unroll
  for (int m=0;m<MMEN;m++){
    const float4* p = (const float4*)(attn +
        ((size_t)(i*HH + head)*CL + mp[m])*CL + j8*8);
    float4 a = p[0], b = p[1];
    acc[0]+=a.x; acc[1]+=a.y; acc[2]+=a.z; acc[3]+=a.w;
    acc[4]+=b.x; acc[5]+=b.y; acc[6]+=b.z; acc[7]+=b.w;
  }
  unsigned o[4];
  #pragma unroll
  for (int q=0;q<4;q++){
    unsigned lo = f_to_bf16u(acc[2*q]   * (1.f/MMEN));
    unsigned hi = f_to_bf16u(acc[2*q+1] * (1.f/MMEN));
    o[q] = lo | (hi<<16);
  }
  ((uint4*)ent_att_bf)[idx] = make_uint4(o[0],o[1],o[2],o[3]);
}

// ---------------------------------------------------------------
// 3. u_ht[p,j] = mean_head ha*ta  (UNNORMALIZED, bf16) + row sums S[p].
//    Normalization is folded into k_gemm_rs's epilogue (rs rows scale
//    linearly by 1/S). grid (16 jt, 4 ps, 4 doc); 4 thr/pair x 16 j.
// ---------------------------------------------------------------
__global__ __launch_bounds__(256) void k_ht_att(const u16* __restrict__ ent_att_bf,
    const int* __restrict__ hts, u16* __restrict__ u_ht_bf, float* __restrict__ S)
{
  const int j0  = blockIdx.x*64;
  const int pb  = blockIdx.y*64;
  const int doc = blockIdx.z;
  const int tid = threadIdx.x;
  const int p_local = tid >> 2, quad = tid & 3;
  const int grow = doc*PP + pb + p_local;
  const int he = hts[grow*2+0], te = hts[grow*2+1];
  const u16* ha = ent_att_bf + ((size_t)(doc*EE + he)*HH)*CL;
  const u16* ta = ent_att_bf + ((size_t)(doc*EE + te)*HH)*CL;
  const int jj = j0 + quad*16;

  float acc[16] = {};
  #pragma unroll
  for (int h=0; h<HH; h++){
    const uint4* pa = (const uint4*)(ha + h*CL + jj);
    const uint4* pb4 = (const uint4*)(ta + h*CL + jj);
    uint4 a0 = pa[0], a1 = pa[1];
    uint4 b0 = pb4[0], b1 = pb4[1];
    unsigned ua[8] = {a0.x,a0.y,a0.z,a0.w,a1.x,a1.y,a1.z,a1.w};
    unsigned ub[8] = {b0.x,b0.y,b0.z,b0.w,b1.x,b1.y,b1.z,b1.w};
    #pragma unroll
    for (int q=0;q<8;q++){
      acc[2*q]   += bf16u_to_f(ua[q]&0xffffu) * bf16u_to_f(ub[q]&0xffffu);
      acc[2*q+1] += bf16u_to_f(ua[q]>>16)     * bf16u_to_f(ub[q]>>16);
    }
  }
  float sum = 0.f;
  unsigned o[8];
  #pragma unroll
  for (int q=0;q<8;q++){
    float v0 = acc[2*q]   * (1.f/HH);
    float v1 = acc[2*q+1] * (1.f/HH);
    sum += v0 + v1;
    o[q] = f_to_bf16u(v0) | (f_to_bf16u(v1)<<16);
  }
  uint4* dst = (uint4*)(u_ht_bf + (size_t)grow*CL + jj);
  dst[0] = make_uint4(o[0],o[1],o[2],o[3]);
  dst[1] = make_uint4(o[4],o[5],o[6],o[7]);
  sum += __shfl_xor(sum, 1, 64);
  sum += __shfl_xor(sum, 2, 64);
  if (quad == 0) atomicAdd(&S[grow], sum);
}

// ---------------------------------------------------------------
// 3b. transpose+convert: dst_bf16[C][R] = src_f32[R][C], batched over z
// ---------------------------------------------------------------
__global__ __launch_bounds__(256) void k_transpose_bf(const float* __restrict__ src,
    u16* __restrict__ dst, int R, int C)
{
  size_t boff = (size_t)blockIdx.z * R * C;
  src += boff; dst += boff;
  __shared__ float t[32][33];
  int tx = threadIdx.x & 31, ty = threadIdx.x >> 5;   // ty 0..7
  int c0 = blockIdx.x*32, r0 = blockIdx.y*32;
  #pragma unroll
  for (int q=0;q<4;q++)
    t[ty+8*q][tx] = src[(size_t)(r0+ty+8*q)*C + c0+tx];
  __syncthreads();
  #pragma unroll
  for (int q=0;q<4;q++)
    dst[(size_t)(c0+ty+8*q)*R + r0+tx] = (u16)f_to_bf16u(t[tx][ty+8*q]);
}

// 3c. same, but src/dst selected by blockIdx.z (for W_head / W_tail)
__global__ __launch_bounds__(256) void k_transpose_bf_w(
    const float* __restrict__ srcA, u16* __restrict__ dstA,
    const float* __restrict__ srcB, u16* __restrict__ dstB, int R, int C)
{
  const float* src = blockIdx.z ? srcB : srcA;
  u16* dst         = blockIdx.z ? dstB : dstA;
  __shared__ float t[32][33];
  int tx = threadIdx.x & 31, ty = threadIdx.x >> 5;
  int c0 = blockIdx.x*32, r0 = blockIdx.y*32;
  #pragma unroll
  for (int q=0;q<4;q++)
    t[ty+8*q][tx] = src[(size_t)(r0+ty+8*q)*C + c0+tx];
  __syncthreads();
  #pragma unroll
  for (int q=0;q<4;q++)
    dst[(size_t)(c0+ty+8*q)*R + r0+tx] = (u16)f_to_bf16u(t[tx][ty+8*q]);
}

// ---------------------------------------------------------------
// 4. rs_bf = bf16( (1/S_row) * (u_ht @ seq) ) via MFMA.
//    BM=128 BN=64 BK=32; grid (2,12,4). Row-normalization in epilogue.
// ---------------------------------------------------------------
__global__ __launch_bounds__(256) void k_gemm_rs_mfma(
    const u16* __restrict__ u_ht_bf, const u16* __restrict__ seq_t_bf,
    const float* __restrict__ S, u16* __restrict__ rs_bf)
{
  const int rt = blockIdx.x, ct = blockIdx.y, doc = blockIdx.z;
  const u16* A  = u_ht_bf + (size_t)doc*PP*CL;
  const u16* Bt = seq_t_bf + (size_t)doc*DD*CL;
  const int row0 = rt*128, col0 = ct*64;
  __shared__ __align__(16) u16 As[128*32];
  __shared__ __align__(16) u16 Bs[64*32];
  const int tid = threadIdx.x, lane = tid & 63, wave = tid >> 6;
  const int m = lane & 15, j8 = lane >> 4;
  const int srow = lane >> 2, schunk = lane & 3;
  f32x4 acc[2][4];
  #pragma unroll
  for (int a=0;a<2;a++)
    #pragma unroll
    for (int b=0;b<4;b++) acc[a][b] = (f32x4){0.f,0.f,0.f,0.f};

  for (int k0 = 0; k0 < CL; k0 += 32){
    __syncthreads();
    #pragma unroll
    for (int ii=0; ii<2; ii++){
      int i = wave*2 + ii;
      int row = i*16 + srow;
      int gc = schunk ^ ((row>>1)&3);
      const u16* gp = A + (size_t)(row0+row)*CL + k0 + gc*8;
      GLOAD_LDS16(gp, &As[i*16*32]);
    }
    {
      int row = wave*16 + srow;
      int gc = schunk ^ ((row>>1)&3);
      const u16* gp = Bt + (size_t)(col0+row)*CL + k0 + gc*8;
      GLOAD_LDS16(gp, &Bs[wave*16*32]);
    }
    __syncthreads();
    short8 af[2], bf[4];
    #pragma unroll
    for (int mf=0; mf<2; mf++){
      int r = wave*32 + mf*16 + m;
      af[mf] = *(const short8*)&As[r*32 + 8*(j8 ^ ((r>>1)&3))];
    }
    #pragma unroll
    for (int nt=0; nt<4; nt++){
      int n = nt*16 + m;
      bf[nt] = *(const short8*)&Bs[n*32 + 8*(j8 ^ ((n>>1)&3))];
    }
    #pragma unroll
    for (int mf=0; mf<2; mf++)
      #pragma unroll
      for (int nt=0; nt<4; nt++)
        acc[mf][nt] = __builtin_amdgcn_mfma_f32_16x16x32_bf16(af[mf], bf[nt], acc[mf][nt], 0,0,0);
  }

  #pragma unroll
  for (int mf=0; mf<2; mf++){
    #pragma unroll
    for (int nt=0; nt<4; nt++){
      int colg = col0 + nt*16 + m;
      #pragma unroll
      for (int reg=0; reg<4; reg++){
        int rowg = doc*PP + row0 + wave*32 + mf*16 + j8*4 + reg;
        float sc = 1.f / (S[rowg] + 1e-30f);
        rs_bf[(size_t)rowg*DD + colg] = (u16)f_to_bf16u(acc[mf][nt][reg] * sc);
      }
    }
  }
}

// ---------------------------------------------------------------
// 5. hs2b = bf16(tanh([ent_emb|rs] @ W_head + b_head)); ts2b analogous.
//    A is gathered on the fly during global_load_lds staging (per-lane
//    global addresses; LDS dest stays wave-uniform+lane*16).
//    BM=128 BN=64 BK=32; grid (8,12,2).
// ---------------------------------------------------------------
__global__ __launch_bounds__(256) void k_gemm_ht_mfma(
    const u16* __restrict__ ent_emb_bf, const u16* __restrict__ rs_bf,
    const int* __restrict__ hts,
    const u16* __restrict__ Wht, const u16* __restrict__ Wtt,
    const float* __restrict__ b_head, const float* __restrict__ b_tail,
    u16* __restrict__ hs2b, u16* __restrict__ ts2b)
{
  const int rt = blockIdx.x, ct = blockIdx.y, z = blockIdx.z;
  const u16* Bt   = z ? Wtt : Wht;
  const float* bias = z ? b_tail : b_head;
  u16* C          = z ? ts2b : hs2b;
  const int row0 = rt*128, col0 = ct*64;
  __shared__ __align__(16) u16 As[128*32];
  __shared__ __align__(16) u16 Bs[64*32];
  const int tid = threadIdx.x, lane = tid & 63, wave = tid >> 6;
  const int m = lane & 15, j8 = lane >> 4;
  const int srow = lane >> 2, schunk = lane & 3;

  // per-thread A-staging row bases (gather fused here)
  const u16* gEnt[2]; const u16* gRs[2]; int gcA[2];
  #pragma unroll
  for (int ii=0; ii<2; ii++){
    int row  = (wave*2+ii)*16 + srow;
    int grow = row0 + row;
    int ent  = hts[grow*2 + z];
    gEnt[ii] = ent_emb_bf + ((size_t)((grow>>8)*EE + ent))*DD;
    gRs[ii]  = rs_bf + (size_t)grow*DD;
    gcA[ii]  = (schunk ^ ((row>>1)&3)) * 8;
  }
  int gcB;
  {
    int row = wave*16 + srow;
    gcB = (schunk ^ ((row>>1)&3)) * 8;
  }

  f32x4 acc[2][4];
  #pragma unroll
  for (int a=0;a<2;a++)
    #pragma unroll
    for (int b=0;b<4;b++) acc[a][b] = (f32x4){0.f,0.f,0.f,0.f};

  for (int k0 = 0; k0 < 1536; k0 += 32){
    __syncthreads();
    #pragma unroll
    for (int ii=0; ii<2; ii++){
      const u16* gp = (k0 < DD) ? (gEnt[ii] + k0 + gcA[ii])
                                : (gRs[ii] + (k0-DD) + gcA[ii]);
      GLOAD_LDS16(gp, &As[(wave*2+ii)*16*32]);
    }
    {
      int row = wave*16 + srow;
      const u16* gp = Bt + (size_t)(col0+row)*1536 + k0 + gcB;
      GLOAD_LDS16(gp, &Bs[wave*16*32]);
    }
    __syncthreads();
    short8 af[2], bf[4];
    #pragma unroll
    for (int mf=0; mf<2; mf++){
      int r = wave*32 + mf*16 + m;
      af[mf] = *(const short8*)&As[r*32 + 8*(j8 ^ ((r>>1)&3))];
    }
    #pragma unroll
    for (int nt=0; nt<4; nt++){
      int n = nt*16 + m;
      bf[nt] = *(const short8*)&Bs[n*32 + 8*(j8 ^ ((n>>1)&3))];
    }
    #pragma unroll
    for (int mf=0; mf<2; mf++)
      #pragma unroll
      for (int nt=0; nt<4; nt++)
        acc[mf][nt] = __builtin_amdgcn_mfma_f32_16x16x32_bf16(af[mf], bf[nt], acc[mf][nt], 0,0,0);
  }

  #pragma unroll
  for (int mf=0; mf<2; mf++){
    #pragma unroll
    for (int nt=0; nt<4; nt++){
      int colg = col0 + nt*16 + m;
      float bv = bias[colg];
      #pragma unroll
      for (int reg=0; reg<4; reg++){
        int rowg = row0 + wave*32 + mf*16 + j8*4 + reg;
        C[(size_t)rowg*DD + colg] = (u16)f_to_bf16u(tanhf(acc[mf][nt][reg] + bv));
      }
    }
  }
}

// ---------------------------------------------------------------
// 6. Wt2: chunked, transposed, padded bf16 image of W_bil.
// ---------------------------------------------------------------
__global__ __launch_bounds__(256) void k_wt2(const float* __restrict__ W_bil,
    u16* __restrict__ Wt2)
{
  const int cc = blockIdx.x;          // 0..1535
  __shared__ u16 lds2[4480];
  int tid = threadIdx.x;
  for (int u=tid; u<4480; u+=256) lds2[u] = 0;
  __syncthreads();
  for (int u=tid; u<112*32; u+=256){
    int kk = u / 112, n = u % 112;
    if (n < OUTD)
      lds2[n*40 + kk] = (u16)f_to_bf16u(W_bil[(size_t)(cc*32 + kk)*OUTD + n]);
  }
  __syncthreads();
  uint4* dst = (uint4*)(Wt2 + (size_t)cc*4480);
  const uint4* src = (const uint4*)lds2;
  for (int v=tid; v<560; v+=256) dst[v] = src[v];
}

// ---------------------------------------------------------------
// 7. bilinear via bf16 MFMA 16x16x32; atomic-free split-K partials.
// ---------------------------------------------------------------
__global__ __launch_bounds__(256) void k_bilinear(
    const u16* __restrict__ hs2b, const u16* __restrict__ ts2b,
    const u16* __restrict__ Wt2, float* __restrict__ pbuf)
{
  const int rt = blockIdx.x;          // 0..7   (128 rows each)
  const int sp = blockIdx.y;          // 0..47  (K range [sp*1024, +1024))
  const int kb = sp >> 2;             // 0..11
  const int i0 = (sp & 3) * 16;       // i base within this kb
  const int row0 = rt * 128;

  __shared__ __align__(16) u16 b1s[128][24];   // 6144 B (pad 24 for bank spread)
  __shared__ __align__(16) u16 b2s[128][72];   // 18432 B
  __shared__ __align__(16) u16 Ws[4480];       // 8960 B

  const int tid = threadIdx.x;
  const int lane = tid & 63, wave = tid >> 6;
  const int m = lane & 15, j8 = lane >> 4;

  // stage b1 (16 bf16/row) and b2 (64 bf16/row) via uint4 copies
  {
    int r = tid >> 1, half = tid & 1;
    uint4 v = *(const uint4*)&hs2b[(size_t)(row0+r)*EMBD + kb*64 + i0 + half*8];
    *(uint4*)&b1s[r][half*8] = v;
  }
  for (int u=tid; u<1024; u+=256){
    int r = u >> 3, seg = u & 7;
    uint4 v = *(const uint4*)&ts2b[(size_t)(row0+r)*EMBD + kb*64 + seg*8];
    *(uint4*)&b2s[r][seg*8] = v;
  }

  const uint4* gsrc = (const uint4*)(Wt2 + (size_t)(sp*32)*4480);
  uint4* ws4 = (uint4*)Ws;
  uint4 pf0, pf1, pf2;
  {
    pf0 = gsrc[tid];
    pf1 = gsrc[tid+256];
    if (tid < 48) pf2 = gsrc[tid+512];
  }

  f32x4 acc[2][7];
  #pragma unroll
  for (int f=0;f<2;f++)
    #pragma unroll
    for (int nt=0;nt<7;nt++) acc[f][nt] = (f32x4){0.f,0.f,0.f,0.f};

  for (int c=0; c<32; c++){
    __syncthreads();
    ws4[tid] = pf0; ws4[tid+256] = pf1; if (tid < 48) ws4[tid+512] = pf2;
    if (c+1 < 32){
      size_t b = (size_t)(c+1)*560;
      pf0 = gsrc[b+tid];
      pf1 = gsrc[b+tid+256];
      if (tid < 48) pf2 = gsrc[b+tid+512];
    }
    __syncthreads();

    const int i_rel = c >> 1;
    const int j0 = (c & 1) * 32;

    short8 bfr[7];
    #pragma unroll
    for (int nt=0;nt<7;nt++)
      bfr[nt] = *(const short8*)&Ws[(nt*16 + m)*40 + j8*8];

    #pragma unroll
    for (int f=0;f<2;f++){
      int r = wave*32 + f*16 + m;
      float s = bf16u_to_f(b1s[r][i_rel]);
      uint4 u = *(const uint4*)&b2s[r][j0 + j8*8];
      unsigned uw[4] = {u.x, u.y, u.z, u.w};
      short8 af;
      #pragma unroll
      for (int e=0;e<4;e++){
        af[2*e]   = (short)f_to_bf16u(s * bf16u_to_f(uw[e] & 0xffffu));
        af[2*e+1] = (short)f_to_bf16u(s * bf16u_to_f(uw[e] >> 16));
      }
      #pragma unroll
      for (int nt=0;nt<7;nt++)
        acc[f][nt] = __builtin_amdgcn_mfma_f32_16x16x32_bf16(af, bfr[nt], acc[f][nt], 0, 0, 0);
    }
  }

  // epilogue: plain stores to partial buffer (no atomics)
  float* dst = pbuf + ((size_t)sp*RTOT + row0)*112;
  #pragma unroll
  for (int f=0;f<2;f++){
    #pragma unroll
    for (int nt=0;nt<7;nt++){
      int col = nt*16 + m;
      #pragma unroll
      for (int reg=0;reg<4;reg++){
        int lrow = wave*32 + f*16 + j8*4 + reg;
        dst[(size_t)lrow*112 + col] = acc[f][nt][reg];
      }
    }
  }
}

// ---------------------------------------------------------------
// 8. reduce partials + bias -> logits
// ---------------------------------------------------------------
__global__ __launch_bounds__(256) void k_reduce_logits(
    const float* __restrict__ pbuf, const float* __restrict__ b_bil,
    float* __restrict__ logits)
{
  int idx = blockIdx.x*256 + threadIdx.x;   // over RTOT*112
  if (idx >= RTOT*112) return;
  int col = idx % 112, row = idx / 112;
  if (col >= OUTD) return;
  float s0 = 0.f, s1 = 0.f, s2 = 0.f, s3 = 0.f;
  const size_t stride = (size_t)RTOT*112;
  #pragma unroll
  for (int sp=0; sp<NSPLIT; sp+=4){
    s0 += pbuf[(sp+0)*stride + idx];
    s1 += pbuf[(sp+1)*stride + idx];
    s2 += pbuf[(sp+2)*stride + idx];
    s3 += pbuf[(sp+3)*stride + idx];
  }
  logits[(size_t)row*OUTD + col] = (s0+s1) + (s2+s3) + b_bil[col];
}

// ---------------------------------------------------------------
extern "C" void kernel_launch(void* const* d_in, const int* in_sizes, int n_in,
                              void* d_out, int out_size, void* d_ws, size_t ws_size,
                              hipStream_t stream)
{
  const float* seq    = (const float*)d_in[0];
  const float* attn   = (const float*)d_in[1];
  const int*   mpos   = (const int*)d_in[2];
  const int*   hts    = (const int*)d_in[3];
  const float* W_head = (const float*)d_in[4];
  const float* b_head = (const float*)d_in[5];
  const float* W_tail = (const float*)d_in[6];
  const float* b_tail = (const float*)d_in[7];
  const float* W_bil  = (const float*)d_in[8];
  const float* b_bil  = (const float*)d_in[9];
  float* logits = (float*)d_out;

  float* ws = (float*)d_ws;
  // float-unit offsets (all 16B-aligned)
  u16*   ent_emb_bf = (u16*)(ws + 0);          //  98304 u16 ->  49152 f
  float* S          = ws + 49152;              //   1024 f
  u16*   rs_bf      = (u16*)(ws + 50176);      // 786432 u16 -> 393216 f
  u16*   hs2b       = (u16*)(ws + 443392);     // 786432 u16 -> 393216 f
  u16*   ts2b       = (u16*)(ws + 836608);     // 786432 u16 -> 393216 f
  u16*   Wh_t       = (u16*)(ws + 1229824);    // 1179648 u16 -> 589824 f
  u16*   Wt_t       = (u16*)(ws + 1819648);    // 1179648 u16 -> 589824 f
  u16*   ent_att_bf = (u16*)(ws + 2409472);    // 1572864 u16 -> 786432 f
  u16*   u_ht_bf    = (u16*)(ws + 3195904);    // 1048576 u16 -> 524288 f
  u16*   seq_t_bf   = (u16*)(ws + 3720192);    // 3145728 u16 -> 1572864 f
  u16*   Wt2        = (u16*)(ws + 5293056);    // 6881280 u16 -> 3440640 f
  float* pbuf       = ws + 8733696;            // 5505024 f
  // total: 14,238,720 floats = 54.3 MiB

  k_ent_emb<<<(ND*EE*DD+255)/256, 256, 0, stream>>>(seq, mpos, ent_emb_bf, S);
  k_ent_att<<<(ND*EE*HH*(CL/8)+255)/256, 256, 0, stream>>>(attn, mpos, ent_att_bf);
  k_ht_att<<<dim3(16, 4, 4), 256, 0, stream>>>(ent_att_bf, hts, u_ht_bf, S);
  k_transpose_bf<<<dim3(DD/32, CL/32, ND), 256, 0, stream>>>(seq, seq_t_bf, CL, DD);
  k_transpose_bf_w<<<dim3(DD/32, 1536/32, 2), 256, 0, stream>>>(
      W_head, Wh_t, W_tail, Wt_t, 1536, DD);
  k_gemm_rs_mfma<<<dim3(2, 12, 4), 256, 0, stream>>>(u_ht_bf, seq_t_bf, S, rs_bf);
  k_gemm_ht_mfma<<<dim3(8, 12, 2), 256, 0, stream>>>(ent_emb_bf, rs_bf, hts,
      Wh_t, Wt_t, b_head, b_tail, hs2b, ts2b);
  k_wt2<<<1536, 256, 0, stream>>>(W_bil, Wt2);
  k_bilinear<<<dim3(RTOT/128, NSPLIT), 256, 0, stream>>>(hs2b, ts2b, Wt2, pbuf);
  k_reduce_logits<<<(RTOT*112+255)/256, 256, 0, stream>>>(pbuf, b_bil, logits);
}

// Round 6
// 359.312 us; speedup vs baseline: 2.5696x; 1.0238x over previous
//
#include <hip/hip_runtime.h>
#include <hip/hip_bf16.h>
#include <math.h>

// Problem constants (from reference setup_inputs)
#define ND 4      // batch n
#define CL 1024   // sequence length c
#define DD 768    // hidden d
#define HH 12     // heads h
#define EE 32     // entities E
#define MMEN 4    // mentions M
#define PP 256    // pairs P
#define EMBD 768  // EMB
#define KBL 12    // K = EMB/BLOCK
#define OUTD 97   // output classes
#define RTOT (ND*PP)  // 1024 rows
#define NSPLIT 48     // bilinear split-K factor

typedef unsigned short u16;
typedef __attribute__((ext_vector_type(8))) short short8;
typedef __attribute__((ext_vector_type(8))) _Float16 half8;
typedef __attribute__((ext_vector_type(4))) float f32x4;

static __device__ inline float bf16u_to_f(unsigned v){
  union { unsigned u; float f; } c; c.u = v << 16; return c.f;
}
static __device__ inline unsigned f_to_bf16u(float f){
  union { float f; unsigned u; } c; c.f = f;
  return (c.u + 0x7fffu + ((c.u >> 16) & 1u)) >> 16;
}
static __device__ inline u16 f_to_f16u(float f){
  _Float16 h = (_Float16)f;
  union { _Float16 h; u16 u; } c; c.h = h; return c.u;
}

#define GLOAD_LDS16(gp, lp) __builtin_amdgcn_global_load_lds( \
    (const __attribute__((address_space(1))) unsigned*)(gp), \
    (__attribute__((address_space(3))) unsigned*)(lp), 16, 0, 0)

// ---------------------------------------------------------------
// 1. ent_emb_bf[i,e,dd] = bf16( logsumexp_m seq[i, mpos[i,e,m], dd] )
//    also zeroes S[1024]
// ---------------------------------------------------------------
__global__ __launch_bounds__(256) void k_ent_emb(const float* __restrict__ seq,
    const int* __restrict__ mpos, u16* __restrict__ ent_emb_bf,
    float* __restrict__ S)
{
  int idx = blockIdx.x*256 + threadIdx.x;
  if (idx >= ND*EE*DD) return;
  if (idx < RTOT) S[idx] = 0.f;
  int dd = idx % DD;
  int e  = (idx / DD) % EE;
  int i  = idx / (DD*EE);
  const int* mp = mpos + (i*EE + e)*MMEN;
  float v[MMEN];
  float mx = -1e30f;
  #pragma unroll
  for (int m=0;m<MMEN;m++){
    v[m] = seq[(i*CL + mp[m])*DD + dd];
    mx = fmaxf(mx, v[m]);
  }
  float s = 0.f;
  #pragma unroll
  for (int m=0;m<MMEN;m++) s += expf(v[m]-mx);
  ent_emb_bf[idx] = (u16)f_to_bf16u(mx + logf(s));
}

// ---------------------------------------------------------------
// 2. ent_att_bf[i,e,head,j] = bf16( mean_m attn[i, head, mpos[i,e,m], j] )
// ---------------------------------------------------------------
__global__ __launch_bounds__(256) void k_ent_att(const float* __restrict__ attn,
    const int* __restrict__ mpos, u16* __restrict__ ent_att_bf)
{
  int idx = blockIdx.x*256 + threadIdx.x;     // over ND*EE*HH*(CL/8)
  if (idx >= ND*EE*HH*(CL/8)) return;
  int j8   = idx % (CL/8);
  int head = (idx / (CL/8)) % HH;
  int e    = (idx / (CL/8*HH)) % EE;
  int i    = idx / (CL/8*HH*EE);
  const int* mp = mpos + (i*EE + e)*MMEN;
  float acc[8] = {};
  #pragma unroll
  for (int m=0;m<MMEN;m++){
    const float4* p = (const float4*)(attn +
        ((size_t)(i*HH + head)*CL + mp[m])*CL + j8*8);
    float4 a = p[0], b = p[1];
    acc[0]+=a.x; acc[1]+=a.y; acc[2]+=a.z; acc[3]+=a.w;
    acc[4]+=b.x; acc[5]+=b.y; acc[6]+=b.z; acc[7]+=b.w;
  }
  unsigned o[4];
  #pragma unroll
  for (int q=0;q<4;q++){
    unsigned lo = f_to_bf16u(acc[2*q]   * (1.f/MMEN));
    unsigned hi = f_to_bf16u(acc[2*q+1] * (1.f/MMEN));
    o[q] = lo | (hi<<16);
  }
  ((uint4*)ent_att_bf)[idx] = make_uint4(o[0],o[1],o[2],o[3]);
}

// ---------------------------------------------------------------
// 3. u_ht[p,j] = mean_head ha*ta (unnormalized bf16) + row sums S[p].
// ---------------------------------------------------------------
__global__ __launch_bounds__(256) void k_ht_att(const u16* __restrict__ ent_att_bf,
    const int* __restrict__ hts, u16* __restrict__ u_ht_bf, float* __restrict__ S)
{
  const int j0  = blockIdx.x*64;
  const int pb  = blockIdx.y*64;
  const int doc = blockIdx.z;
  const int tid = threadIdx.x;
  const int p_local = tid >> 2, quad = tid & 3;
  const int grow = doc*PP + pb + p_local;
  const int he = hts[grow*2+0], te = hts[grow*2+1];
  const u16* ha = ent_att_bf + ((size_t)(doc*EE + he)*HH)*CL;
  const u16* ta = ent_att_bf + ((size_t)(doc*EE + te)*HH)*CL;
  const int jj = j0 + quad*16;

  float acc[16] = {};
  #pragma unroll
  for (int h=0; h<HH; h++){
    const uint4* pa = (const uint4*)(ha + h*CL + jj);
    const uint4* pb4 = (const uint4*)(ta + h*CL + jj);
    uint4 a0 = pa[0], a1 = pa[1];
    uint4 b0 = pb4[0], b1 = pb4[1];
    unsigned ua[8] = {a0.x,a0.y,a0.z,a0.w,a1.x,a1.y,a1.z,a1.w};
    unsigned ub[8] = {b0.x,b0.y,b0.z,b0.w,b1.x,b1.y,b1.z,b1.w};
    #pragma unroll
    for (int q=0;q<8;q++){
      acc[2*q]   += bf16u_to_f(ua[q]&0xffffu) * bf16u_to_f(ub[q]&0xffffu);
      acc[2*q+1] += bf16u_to_f(ua[q]>>16)     * bf16u_to_f(ub[q]>>16);
    }
  }
  float sum = 0.f;
  unsigned o[8];
  #pragma unroll
  for (int q=0;q<8;q++){
    float v0 = acc[2*q]   * (1.f/HH);
    float v1 = acc[2*q+1] * (1.f/HH);
    sum += v0 + v1;
    o[q] = f_to_bf16u(v0) | (f_to_bf16u(v1)<<16);
  }
  uint4* dst = (uint4*)(u_ht_bf + (size_t)grow*CL + jj);
  dst[0] = make_uint4(o[0],o[1],o[2],o[3]);
  dst[1] = make_uint4(o[4],o[5],o[6],o[7]);
  sum += __shfl_xor(sum, 1, 64);
  sum += __shfl_xor(sum, 2, 64);
  if (quad == 0) atomicAdd(&S[grow], sum);
}

// ---------------------------------------------------------------
// 3b. transpose+convert: dst_bf16[C][R] = src_f32[R][C], batched over z
// ---------------------------------------------------------------
__global__ __launch_bounds__(256) void k_transpose_bf(const float* __restrict__ src,
    u16* __restrict__ dst, int R, int C)
{
  size_t boff = (size_t)blockIdx.z * R * C;
  src += boff; dst += boff;
  __shared__ float t[32][33];
  int tx = threadIdx.x & 31, ty = threadIdx.x >> 5;
  int c0 = blockIdx.x*32, r0 = blockIdx.y*32;
  #pragma unroll
  for (int q=0;q<4;q++)
    t[ty+8*q][tx] = src[(size_t)(r0+ty+8*q)*C + c0+tx];
  __syncthreads();
  #pragma unroll
  for (int q=0;q<4;q++)
    dst[(size_t)(c0+ty+8*q)*R + r0+tx] = (u16)f_to_bf16u(t[tx][ty+8*q]);
}

// 3c. same, src/dst selected by blockIdx.z (W_head / W_tail)
__global__ __launch_bounds__(256) void k_transpose_bf_w(
    const float* __restrict__ srcA, u16* __restrict__ dstA,
    const float* __restrict__ srcB, u16* __restrict__ dstB, int R, int C)
{
  const float* src = blockIdx.z ? srcB : srcA;
  u16* dst         = blockIdx.z ? dstB : dstA;
  __shared__ float t[32][33];
  int tx = threadIdx.x & 31, ty = threadIdx.x >> 5;
  int c0 = blockIdx.x*32, r0 = blockIdx.y*32;
  #pragma unroll
  for (int q=0;q<4;q++)
    t[ty+8*q][tx] = src[(size_t)(r0+ty+8*q)*C + c0+tx];
  __syncthreads();
  #pragma unroll
  for (int q=0;q<4;q++)
    dst[(size_t)(c0+ty+8*q)*R + r0+tx] = (u16)f_to_bf16u(t[tx][ty+8*q]);
}

// ---------------------------------------------------------------
// 4. rs_bf = bf16( (1/S_row) * (u_ht @ seq) ) via MFMA.
//    BM=128 BN=64 BK=64; grid (2,12,4). XOR-8 chunk swizzle.
// ---------------------------------------------------------------
__global__ __launch_bounds__(256) void k_gemm_rs_mfma(
    const u16* __restrict__ u_ht_bf, const u16* __restrict__ seq_t_bf,
    const float* __restrict__ S, u16* __restrict__ rs_bf)
{
  const int rt = blockIdx.x, ct = blockIdx.y, doc = blockIdx.z;
  const u16* A  = u_ht_bf + (size_t)doc*PP*CL;
  const u16* Bt = seq_t_bf + (size_t)doc*DD*CL;
  const int row0 = rt*128, col0 = ct*64;
  __shared__ __align__(16) u16 As[128*64];
  __shared__ __align__(16) u16 Bs[64*64];
  const int tid = threadIdx.x, lane = tid & 63, wave = tid >> 6;
  const int m = lane & 15, j8 = lane >> 4;
  const int srow8 = lane >> 3, sc8 = lane & 7;
  f32x4 acc[2][4];
  #pragma unroll
  for (int a=0;a<2;a++)
    #pragma unroll
    for (int b=0;b<4;b++) acc[a][b] = (f32x4){0.f,0.f,0.f,0.f};

  for (int k0 = 0; k0 < CL; k0 += 64){
    __syncthreads();
    #pragma unroll
    for (int ii=0; ii<4; ii++){
      int row = ii*32 + wave*8 + srow8;
      int gc = sc8 ^ (row & 7);
      const u16* gp = A + (size_t)(row0+row)*CL + k0 + gc*8;
      GLOAD_LDS16(gp, &As[(ii*32 + wave*8)*64]);
    }
    #pragma unroll
    for (int ii=0; ii<2; ii++){
      int row = ii*32 + wave*8 + srow8;
      int gc = sc8 ^ (row & 7);
      const u16* gp = Bt + (size_t)(col0+row)*CL + k0 + gc*8;
      GLOAD_LDS16(gp, &Bs[(ii*32 + wave*8)*64]);
    }
    __syncthreads();
    #pragma unroll
    for (int h=0; h<2; h++){
      short8 af[2], bf[4];
      #pragma unroll
      for (int mf=0; mf<2; mf++){
        int r = wave*32 + mf*16 + m;
        int c = (h*4 + j8) ^ (r & 7);
        af[mf] = *(const short8*)&As[r*64 + c*8];
      }
      #pragma unroll
      for (int nt=0; nt<4; nt++){
        int n = nt*16 + m;
        int c = (h*4 + j8) ^ (n & 7);
        bf[nt] = *(const short8*)&Bs[n*64 + c*8];
      }
      #pragma unroll
      for (int mf=0; mf<2; mf++)
        #pragma unroll
        for (int nt=0; nt<4; nt++)
          acc[mf][nt] = __builtin_amdgcn_mfma_f32_16x16x32_bf16(af[mf], bf[nt], acc[mf][nt], 0,0,0);
    }
  }

  #pragma unroll
  for (int mf=0; mf<2; mf++){
    #pragma unroll
    for (int nt=0; nt<4; nt++){
      int colg = col0 + nt*16 + m;
      #pragma unroll
      for (int reg=0; reg<4; reg++){
        int rowg = doc*PP + row0 + wave*32 + mf*16 + j8*4 + reg;
        float sc = 1.f / (S[rowg] + 1e-30f);
        rs_bf[(size_t)rowg*DD + colg] = (u16)f_to_bf16u(acc[mf][nt][reg] * sc);
      }
    }
  }
}

// ---------------------------------------------------------------
// 5. hs2h = f16(tanh([ent_emb|rs] @ W_head + b_head)); ts2h analogous.
//    Gather fused into staging. BM=128 BN=64 BK=64; grid (8,12,2).
// ---------------------------------------------------------------
__global__ __launch_bounds__(256) void k_gemm_ht_mfma(
    const u16* __restrict__ ent_emb_bf, const u16* __restrict__ rs_bf,
    const int* __restrict__ hts,
    const u16* __restrict__ Wht, const u16* __restrict__ Wtt,
    const float* __restrict__ b_head, const float* __restrict__ b_tail,
    u16* __restrict__ hs2h, u16* __restrict__ ts2h)
{
  const int rt = blockIdx.x, ct = blockIdx.y, z = blockIdx.z;
  const u16* Bt   = z ? Wtt : Wht;
  const float* bias = z ? b_tail : b_head;
  u16* C          = z ? ts2h : hs2h;
  const int row0 = rt*128, col0 = ct*64;
  __shared__ __align__(16) u16 As[128*64];
  __shared__ __align__(16) u16 Bs[64*64];
  const int tid = threadIdx.x, lane = tid & 63, wave = tid >> 6;
  const int m = lane & 15, j8 = lane >> 4;
  const int srow8 = lane >> 3, sc8 = lane & 7;

  // per-thread A-staging row bases (gather fused)
  const u16* gEnt[4]; const u16* gRs[4]; int gcA[4];
  #pragma unroll
  for (int ii=0; ii<4; ii++){
    int row  = ii*32 + wave*8 + srow8;
    int grow = row0 + row;
    int ent  = hts[grow*2 + z];
    gEnt[ii] = ent_emb_bf + ((size_t)((grow>>8)*EE + ent))*DD;
    gRs[ii]  = rs_bf + (size_t)grow*DD;
    gcA[ii]  = (sc8 ^ (row & 7)) * 8;
  }

  f32x4 acc[2][4];
  #pragma unroll
  for (int a=0;a<2;a++)
    #pragma unroll
    for (int b=0;b<4;b++) acc[a][b] = (f32x4){0.f,0.f,0.f,0.f};

  for (int k0 = 0; k0 < 1536; k0 += 64){
    __syncthreads();
    #pragma unroll
    for (int ii=0; ii<4; ii++){
      const u16* gp = (k0 < DD) ? (gEnt[ii] + k0 + gcA[ii])
                                : (gRs[ii] + (k0-DD) + gcA[ii]);
      GLOAD_LDS16(gp, &As[(ii*32 + wave*8)*64]);
    }
    #pragma unroll
    for (int ii=0; ii<2; ii++){
      int row = ii*32 + wave*8 + srow8;
      int gc = sc8 ^ (row & 7);
      const u16* gp = Bt + (size_t)(col0+row)*1536 + k0 + gc*8;
      GLOAD_LDS16(gp, &Bs[(ii*32 + wave*8)*64]);
    }
    __syncthreads();
    #pragma unroll
    for (int h=0; h<2; h++){
      short8 af[2], bf[4];
      #pragma unroll
      for (int mf=0; mf<2; mf++){
        int r = wave*32 + mf*16 + m;
        int c = (h*4 + j8) ^ (r & 7);
        af[mf] = *(const short8*)&As[r*64 + c*8];
      }
      #pragma unroll
      for (int nt=0; nt<4; nt++){
        int n = nt*16 + m;
        int c = (h*4 + j8) ^ (n & 7);
        bf[nt] = *(const short8*)&Bs[n*64 + c*8];
      }
      #pragma unroll
      for (int mf=0; mf<2; mf++)
        #pragma unroll
        for (int nt=0; nt<4; nt++)
          acc[mf][nt] = __builtin_amdgcn_mfma_f32_16x16x32_bf16(af[mf], bf[nt], acc[mf][nt], 0,0,0);
    }
  }

  #pragma unroll
  for (int mf=0; mf<2; mf++){
    #pragma unroll
    for (int nt=0; nt<4; nt++){
      int colg = col0 + nt*16 + m;
      float bv = bias[colg];
      #pragma unroll
      for (int reg=0; reg<4; reg++){
        int rowg = row0 + wave*32 + mf*16 + j8*4 + reg;
        C[(size_t)rowg*DD + colg] = f_to_f16u(tanhf(acc[mf][nt][reg] + bv));
      }
    }
  }
}

// ---------------------------------------------------------------
// 6. Wt2: chunked, transposed, padded **f16** image of W_bil.
// ---------------------------------------------------------------
__global__ __launch_bounds__(256) void k_wt2(const float* __restrict__ W_bil,
    u16* __restrict__ Wt2)
{
  const int cc = blockIdx.x;          // 0..1535
  __shared__ u16 lds2[4480];
  int tid = threadIdx.x;
  for (int u=tid; u<4480; u+=256) lds2[u] = 0;
  __syncthreads();
  for (int u=tid; u<112*32; u+=256){
    int kk = u / 112, n = u % 112;
    if (n < OUTD)
      lds2[n*40 + kk] = f_to_f16u(W_bil[(size_t)(cc*32 + kk)*OUTD + n]);
  }
  __syncthreads();
  uint4* dst = (uint4*)(Wt2 + (size_t)cc*4480);
  const uint4* src = (const uint4*)lds2;
  for (int v=tid; v<560; v+=256) dst[v] = src[v];
}

// ---------------------------------------------------------------
// 7. bilinear via **f16** MFMA 16x16x32; A-frag = pk_mul(b1 splat, b2).
//    atomic-free split-K partials.
// ---------------------------------------------------------------
__global__ __launch_bounds__(256) void k_bilinear(
    const u16* __restrict__ hs2h, const u16* __restrict__ ts2h,
    const u16* __restrict__ Wt2, float* __restrict__ pbuf)
{
  const int rt = blockIdx.x;          // 0..7   (128 rows each)
  const int sp = blockIdx.y;          // 0..47  (K range [sp*1024, +1024))
  const int kb = sp >> 2;             // 0..11
  const int i0 = (sp & 3) * 16;       // i base within this kb
  const int row0 = rt * 128;

  __shared__ __align__(16) u16 b1s[128][24];   // 6144 B
  __shared__ __align__(16) u16 b2s[128][72];   // 18432 B
  __shared__ __align__(16) u16 Ws[4480];       // 8960 B

  const int tid = threadIdx.x;
  const int lane = tid & 63, wave = tid >> 6;
  const int m = lane & 15, j8 = lane >> 4;

  // stage b1 (16 f16/row) and b2 (64 f16/row) via uint4 copies
  {
    int r = tid >> 1, half = tid & 1;
    uint4 v = *(const uint4*)&hs2h[(size_t)(row0+r)*EMBD + kb*64 + i0 + half*8];
    *(uint4*)&b1s[r][half*8] = v;
  }
  for (int u=tid; u<1024; u+=256){
    int r = u >> 3, seg = u & 7;
    uint4 v = *(const uint4*)&ts2h[(size_t)(row0+r)*EMBD + kb*64 + seg*8];
    *(uint4*)&b2s[r][seg*8] = v;
  }

  const uint4* gsrc = (const uint4*)(Wt2 + (size_t)(sp*32)*4480);
  uint4* ws4 = (uint4*)Ws;
  uint4 pf0, pf1, pf2;
  {
    pf0 = gsrc[tid];
    pf1 = gsrc[tid+256];
    if (tid < 48) pf2 = gsrc[tid+512];
  }

  f32x4 acc[2][7];
  #pragma unroll
  for (int f=0;f<2;f++)
    #pragma unroll
    for (int nt=0;nt<7;nt++) acc[f][nt] = (f32x4){0.f,0.f,0.f,0.f};

  for (int c=0; c<32; c++){
    __syncthreads();
    ws4[tid] = pf0; ws4[tid+256] = pf1; if (tid < 48) ws4[tid+512] = pf2;
    if (c+1 < 32){
      size_t b = (size_t)(c+1)*560;
      pf0 = gsrc[b+tid];
      pf1 = gsrc[b+tid+256];
      if (tid < 48) pf2 = gsrc[b+tid+512];
    }
    __syncthreads();

    const int i_rel = c >> 1;
    const int j0 = (c & 1) * 32;

    half8 bfr[7];
    #pragma unroll
    for (int nt=0;nt<7;nt++)
      bfr[nt] = *(const half8*)&Ws[(nt*16 + m)*40 + j8*8];

    #pragma unroll
    for (int f=0;f<2;f++){
      int r = wave*32 + f*16 + m;
      _Float16 s = *(const _Float16*)&b1s[r][i_rel];
      half8 sv = {s,s,s,s,s,s,s,s};
      half8 b2v = *(const half8*)&b2s[r][j0 + j8*8];
      half8 af = sv * b2v;              // v_pk_mul_f16 x4
      #pragma unroll
      for (int nt=0;nt<7;nt++)
        acc[f][nt] = __builtin_amdgcn_mfma_f32_16x16x32_f16(af, bfr[nt], acc[f][nt], 0, 0, 0);
    }
  }

  // epilogue: plain stores to partial buffer (no atomics)
  float* dst = pbuf + ((size_t)sp*RTOT + row0)*112;
  #pragma unroll
  for (int f=0;f<2;f++){
    #pragma unroll
    for (int nt=0;nt<7;nt++){
      int col = nt*16 + m;
      #pragma unroll
      for (int reg=0;reg<4;reg++){
        int lrow = wave*32 + f*16 + j8*4 + reg;
        dst[(size_t)lrow*112 + col] = acc[f][nt][reg];
      }
    }
  }
}

// ---------------------------------------------------------------
// 8. reduce partials + bias -> logits
// ---------------------------------------------------------------
__global__ __launch_bounds__(256) void k_reduce_logits(
    const float* __restrict__ pbuf, const float* __restrict__ b_bil,
    float* __restrict__ logits)
{
  int idx = blockIdx.x*256 + threadIdx.x;   // over RTOT*112
  if (idx >= RTOT*112) return;
  int col = idx % 112, row = idx / 112;
  if (col >= OUTD) return;
  float s0 = 0.f, s1 = 0.f, s2 = 0.f, s3 = 0.f;
  const size_t stride = (size_t)RTOT*112;
  #pragma unroll
  for (int sp=0; sp<NSPLIT; sp+=4){
    s0 += pbuf[(sp+0)*stride + idx];
    s1 += pbuf[(sp+1)*stride + idx];
    s2 += pbuf[(sp+2)*stride + idx];
    s3 += pbuf[(sp+3)*stride + idx];
  }
  logits[(size_t)row*OUTD + col] = (s0+s1) + (s2+s3) + b_bil[col];
}

// ---------------------------------------------------------------
extern "C" void kernel_launch(void* const* d_in, const int* in_sizes, int n_in,
                              void* d_out, int out_size, void* d_ws, size_t ws_size,
                              hipStream_t stream)
{
  const float* seq    = (const float*)d_in[0];
  const float* attn   = (const float*)d_in[1];
  const int*   mpos   = (const int*)d_in[2];
  const int*   hts    = (const int*)d_in[3];
  const float* W_head = (const float*)d_in[4];
  const float* b_head = (const float*)d_in[5];
  const float* W_tail = (const float*)d_in[6];
  const float* b_tail = (const float*)d_in[7];
  const float* W_bil  = (const float*)d_in[8];
  const float* b_bil  = (const float*)d_in[9];
  float* logits = (float*)d_out;

  float* ws = (float*)d_ws;
  // float-unit offsets (all 16B-aligned)
  u16*   ent_emb_bf = (u16*)(ws + 0);          //  98304 u16 ->  49152 f
  float* S          = ws + 49152;              //   1024 f
  u16*   rs_bf      = (u16*)(ws + 50176);      // 786432 u16 -> 393216 f
  u16*   hs2h       = (u16*)(ws + 443392);     // 786432 u16 -> 393216 f
  u16*   ts2h       = (u16*)(ws + 836608);     // 786432 u16 -> 393216 f
  u16*   Wh_t       = (u16*)(ws + 1229824);    // 1179648 u16 -> 589824 f
  u16*   Wt_t       = (u16*)(ws + 1819648);    // 1179648 u16 -> 589824 f
  u16*   ent_att_bf = (u16*)(ws + 2409472);    // 1572864 u16 -> 786432 f
  u16*   u_ht_bf    = (u16*)(ws + 3195904);    // 1048576 u16 -> 524288 f
  u16*   seq_t_bf   = (u16*)(ws + 3720192);    // 3145728 u16 -> 1572864 f
  u16*   Wt2        = (u16*)(ws + 5293056);    // 6881280 u16 -> 3440640 f
  float* pbuf       = ws + 8733696;            // 5505024 f
  // total: 14,238,720 floats = 54.3 MiB

  k_ent_emb<<<(ND*EE*DD+255)/256, 256, 0, stream>>>(seq, mpos, ent_emb_bf, S);
  k_ent_att<<<(ND*EE*HH*(CL/8)+255)/256, 256, 0, stream>>>(attn, mpos, ent_att_bf);
  k_ht_att<<<dim3(16, 4, 4), 256, 0, stream>>>(ent_att_bf, hts, u_ht_bf, S);
  k_transpose_bf<<<dim3(DD/32, CL/32, ND), 256, 0, stream>>>(seq, seq_t_bf, CL, DD);
  k_transpose_bf_w<<<dim3(DD/32, 1536/32, 2), 256, 0, stream>>>(
      W_head, Wh_t, W_tail, Wt_t, 1536, DD);
  k_gemm_rs_mfma<<<dim3(2, 12, 4), 256, 0, stream>>>(u_ht_bf, seq_t_bf, S, rs_bf);
  k_gemm_ht_mfma<<<dim3(8, 12, 2), 256, 0, stream>>>(ent_emb_bf, rs_bf, hts,
      Wh_t, Wt_t, b_head, b_tail, hs2h, ts2h);
  k_wt2<<<1536, 256, 0, stream>>>(W_bil, Wt2);
  k_bilinear<<<dim3(RTOT/128, NSPLIT), 256, 0, stream>>>(hs2h, ts2h, Wt2, pbuf);
  k_reduce_logits<<<(RTOT*112+255)/256, 256, 0, stream>>>(pbuf, b_bil, logits);
}